// Round 18
// baseline (851.370 us; speedup 1.0000x reference)
//
#include <hip/hip_runtime.h>

constexpr int Bc = 8, Nc = 4096;

using short8 = __attribute__((ext_vector_type(8))) short;
using f32x4  = __attribute__((ext_vector_type(4))) float;

static __device__ __forceinline__ unsigned short f2bf(float f) {
    unsigned u = __float_as_uint(f);
    u += 0x7fffu + ((u >> 16) & 1u);     // RNE
    return (unsigned short)(u >> 16);
}
// XOR-swizzled byte offset for a [32][256] ushort LDS plane (16B-access safe)
static __device__ __forceinline__ int swz(int r, int k) {
    return (r << 9) + ((k << 1) ^ ((r & 7) << 4));
}

// ---------------- K0a: Wd [h][d][e] f32 -> WdT [h][e][d] bf16 ----------------
__global__ __launch_bounds__(256)
void k0_wdt(const float* __restrict__ Wd, unsigned short* __restrict__ WdT)
{
    __shared__ float tile[64][65];
    const int h  = blockIdx.x >> 4;
    const int t  = blockIdx.x & 15;
    const int kb = (t >> 2) * 64, eb = (t & 3) * 64;
    const int tid = threadIdx.x;
    {
        const int krow = tid >> 2, ec = (tid & 3) * 16;
        const float* src = Wd + h * 65536 + (kb + krow) * 256 + eb + ec;
        #pragma unroll
        for (int i = 0; i < 4; ++i) {
            float4 v = *reinterpret_cast<const float4*>(src + i * 4);
            tile[krow][ec + i * 4 + 0] = v.x;
            tile[krow][ec + i * 4 + 1] = v.y;
            tile[krow][ec + i * 4 + 2] = v.z;
            tile[krow][ec + i * 4 + 3] = v.w;
        }
    }
    __syncthreads();
    {
        const int erow = tid >> 2, dc = (tid & 3) * 16;
        unsigned short o[16];
        #pragma unroll
        for (int i = 0; i < 16; ++i) o[i] = f2bf(tile[dc + i][erow]);
        unsigned short* dst = WdT + h * 65536 + (eb + erow) * 256 + kb + dc;
        *reinterpret_cast<short8*>(dst)     = *reinterpret_cast<short8*>(&o[0]);
        *reinterpret_cast<short8*>(dst + 8) = *reinterpret_cast<short8*>(&o[8]);
    }
}

// ---------------- K0b: Wh [k][h][e] f32 -> WhH bf16 [h][e][k] + WhT f32 [h][e][k] ----------------
__global__ __launch_bounds__(256)
void k0_wht(const float* __restrict__ Wh, unsigned short* __restrict__ WhH,
            float* __restrict__ WhT)
{
    __shared__ float tile[64][65];
    const int h  = blockIdx.x >> 4;
    const int t  = blockIdx.x & 15;
    const int kb = (t >> 2) * 64, eb = (t & 3) * 64;
    const int tid = threadIdx.x;
    {
        const int krow = tid >> 2, ec = (tid & 3) * 16;
        const float* src = Wh + (kb + krow) * 2048 + h * 256 + eb + ec;
        #pragma unroll
        for (int i = 0; i < 4; ++i) {
            float4 v = *reinterpret_cast<const float4*>(src + i * 4);
            tile[krow][ec + i * 4 + 0] = v.x;
            tile[krow][ec + i * 4 + 1] = v.y;
            tile[krow][ec + i * 4 + 2] = v.z;
            tile[krow][ec + i * 4 + 3] = v.w;
        }
    }
    __syncthreads();
    {
        const int erow = tid >> 2, dc = (tid & 3) * 16;
        unsigned short o[16];
        float of[16];
        #pragma unroll
        for (int i = 0; i < 16; ++i) {
            of[i] = tile[dc + i][erow];
            o[i] = f2bf(of[i]);
        }
        const long base = (long)h * 65536 + (eb + erow) * 256 + kb + dc;
        *reinterpret_cast<short8*>(WhH + base)     = *reinterpret_cast<short8*>(&o[0]);
        *reinterpret_cast<short8*>(WhH + base + 8) = *reinterpret_cast<short8*>(&o[8]);
        #pragma unroll
        for (int i = 0; i < 16; i += 4)
            *reinterpret_cast<float4*>(WhT + base + i) = *reinterpret_cast<const float4*>(&of[i]);
    }
}

// ---------------- K0c: Wv [k][e] f32 -> WvT [e][k] bf16 ----------------
__global__ __launch_bounds__(256)
void k0_wvt(const float* __restrict__ Wv, unsigned short* __restrict__ WvT)
{
    __shared__ float tile[64][65];
    const int t  = blockIdx.x;
    const int kb = (t >> 2) * 64, eb = (t & 3) * 64;
    const int tid = threadIdx.x;
    {
        const int krow = tid >> 2, ec = (tid & 3) * 16;
        const float* src = Wv + (kb + krow) * 256 + eb + ec;
        #pragma unroll
        for (int i = 0; i < 4; ++i) {
            float4 v = *reinterpret_cast<const float4*>(src + i * 4);
            tile[krow][ec + i * 4 + 0] = v.x;
            tile[krow][ec + i * 4 + 1] = v.y;
            tile[krow][ec + i * 4 + 2] = v.z;
            tile[krow][ec + i * 4 + 3] = v.w;
        }
    }
    __syncthreads();
    {
        const int erow = tid >> 2, dc = (tid & 3) * 16;
        unsigned short o[16];
        #pragma unroll
        for (int i = 0; i < 16; ++i) o[i] = f2bf(tile[dc + i][erow]);
        unsigned short* dst = WvT + (eb + erow) * 256 + kb + dc;
        *reinterpret_cast<short8*>(dst)     = *reinterpret_cast<short8*>(&o[0]);
        *reinterpret_cast<short8*>(dst + 8) = *reinterpret_cast<short8*>(&o[8]);
    }
}

// LDS layout (bytes) for K1 — total 51840 -> 3 blocks/CU
#define XSH_OFF  0        // [32][256] ushort swz (x bf16)  — dead after h loop
#define QTB_OFF  16384    // [32][256] ushort swz (q bf16)  — dead after h loop
// tail valq[32][256] f32 overlays [0, 32768)
#define LSH8_OFF 32768    // s8[256][32]
#define PE_OFF   40960    // float[256]
#define CF_OFF   41984    // float[256]
#define CNT_OFF  43008    // int[32][16]
#define FCN_OFF  45056    // int
#define CCN_OFF  45060    // int
#define FLS_OFF  45064    // int[1536]
#define CLS_OFF  51208    // int[128]
#define FLS_CAP  1536
#define CLS_CAP  128
#define GUARD    0.012f

// ---------------- K1: bf16-MFMA head GEMM (sign-guarded) + MFMA down GEMM ----------------
__global__ __launch_bounds__(256, 1)
void k1_head_down(const float* __restrict__ x,
                  const float* __restrict__ bh,
                  const float* __restrict__ WhT,
                  const unsigned short* __restrict__ WhH,
                  const unsigned short* __restrict__ WdT, const float* __restrict__ bd,
                  float* __restrict__ z, float* __restrict__ simv)
{
    __shared__ __align__(16) char SM[51840];

    const int tid = threadIdx.x;
    const long rowbase = (long)blockIdx.x * 32;
    const int wavei = tid >> 6, lane = tid & 63;
    const int mrow = lane & 15, kgrp = lane >> 4;
    const int ebase = wavei * 64 + mrow;
    const int kfo = kgrp * 8;

    short8 hB[4][4], dB[4][4];
    #pragma unroll
    for (int i = 0; i < 4; ++i)
        #pragma unroll
        for (int nf = 0; nf < 4; ++nf)
            hB[i][nf] = *reinterpret_cast<const short8*>(
                &WhH[(ebase + nf * 16) * 256 + i * 32 + kfo]);

    {   // XLA:CPU twin tables (CR libm via f64-round) — overlaps with hB flight
        const int d = tid;
        const float u = -((float)d * 0.00390625f);
        const float freq = (float)pow(10.0, (double)u);
        const float pe = (d & 1) ? (float)sin((double)freq)
                                 : (float)cos((double)freq);
        ((float*)(SM + PE_OFF))[d] = __fdiv_rn(pe, 0.4f);
        ((float*)(SM + CF_OFF))[d] = __fmul_rn(0.4f, (float)pow((double)0.6f, (double)d));
    }
    if (tid == 0) { *(int*)(SM + FCN_OFF) = 0; *(int*)(SM + CCN_OFF) = 0; }
    {   // x -> bf16 LDS (swizzled): thread handles row r, 32 k
        const int r = tid >> 3, kc = (tid & 7) * 32;
        const float* src = x + (rowbase + r) * 256 + kc;
        unsigned short oh[32];
        #pragma unroll
        for (int i = 0; i < 32; i += 4) {
            float4 v = *reinterpret_cast<const float4*>(src + i);
            oh[i + 0] = f2bf(v.x); oh[i + 1] = f2bf(v.y);
            oh[i + 2] = f2bf(v.z); oh[i + 3] = f2bf(v.w);
        }
        #pragma unroll
        for (int i = 0; i < 32; i += 8)
            *reinterpret_cast<short8*>(SM + XSH_OFF + swz(r, kc + i)) =
                *reinterpret_cast<short8*>(&oh[i]);
    }

    unsigned lshp[4] = {0u, 0u, 0u, 0u};    // 32 nibble counters (statically indexed)
    f32x4 dacc[2][4];
    #pragma unroll
    for (int mt = 0; mt < 2; ++mt)
        #pragma unroll
        for (int nf = 0; nf < 4; ++nf) dacc[mt][nf] = (f32x4){0.f, 0.f, 0.f, 0.f};

    __syncthreads();

    for (int h = 0; h < 8; ++h) {
        const unsigned short* whh = WhH + ((long)h << 16);
        const unsigned short* wdh = WdT + ((long)h << 16);
        float bias[4];
        #pragma unroll
        for (int nf = 0; nf < 4; ++nf) bias[nf] = bh[(h << 8) + ebase + nf * 16];

        // ---- head GEMM: ring-4 prefetch; down-B slices 0..3 issued here ----
        f32x4 hacc[2][4];
        #pragma unroll
        for (int mt = 0; mt < 2; ++mt)
            #pragma unroll
            for (int nf = 0; nf < 4; ++nf) hacc[mt][nf] = (f32x4){0.f, 0.f, 0.f, 0.f};
        #pragma unroll
        for (int kt = 0; kt < 8; ++kt) {
            const int k0 = kt * 32 + kfo;
            short8 a0 = *reinterpret_cast<const short8*>(SM + XSH_OFF + swz(mrow, k0));
            short8 a1 = *reinterpret_cast<const short8*>(SM + XSH_OFF + swz(16 + mrow, k0));
            if (kt < 4) {
                #pragma unroll
                for (int nf = 0; nf < 4; ++nf)
                    dB[kt][nf] = *reinterpret_cast<const short8*>(
                        &wdh[(ebase + nf * 16) * 256 + kt * 32 + kfo]);
            }
            #pragma unroll
            for (int nf = 0; nf < 4; ++nf) {
                hacc[0][nf] = __builtin_amdgcn_mfma_f32_16x16x32_bf16(a0, hB[kt & 3][nf], hacc[0][nf], 0, 0, 0);
                hacc[1][nf] = __builtin_amdgcn_mfma_f32_16x16x32_bf16(a1, hB[kt & 3][nf], hacc[1][nf], 0, 0, 0);
            }
            if (kt < 4) {
                #pragma unroll
                for (int nf = 0; nf < 4; ++nf)
                    hB[kt][nf] = *reinterpret_cast<const short8*>(
                        &whh[(ebase + nf * 16) * 256 + (kt + 4) * 32 + kfo]);
            }
        }
        // ---- signs / guard-list / qTb ----
        #pragma unroll
        for (int mt = 0; mt < 2; ++mt) {
            #pragma unroll
            for (int nf = 0; nf < 4; ++nf) {
                const int e = ebase + nf * 16;
                #pragma unroll
                for (int reg = 0; reg < 4; ++reg) {
                    const int r = mt * 16 + kgrp * 4 + reg;
                    const float pre = __fadd_rn(hacc[mt][nf][reg], bias[nf]);
                    const unsigned pos = (pre > 0.0f) ? 1u : 0u;
                    const int j = mt * 16 + nf * 4 + reg;
                    lshp[j >> 3] += pos << (4 * (j & 7));
                    if (fabsf(pre) < GUARD) {
                        int idx = atomicAdd((int*)(SM + FCN_OFF), 1);
                        if (idx < FLS_CAP)
                            ((int*)(SM + FLS_OFF))[idx] =
                                r | (e << 5) | (h << 13) | ((int)pos << 16);
                    }
                    *reinterpret_cast<unsigned short*>(SM + QTB_OFF + swz(r, e)) =
                        f2bf(fmaxf(pre, 0.0f));
                }
            }
        }
        __syncthreads();   // qTb ready
        // ---- down GEMM: ring-4; slices 4..7 + next-h head slices issued here ----
        #pragma unroll
        for (int ks = 0; ks < 8; ++ks) {
            const int k0 = ks * 32 + kfo;
            short8 a0 = *reinterpret_cast<const short8*>(SM + QTB_OFF + swz(mrow, k0));
            short8 a1 = *reinterpret_cast<const short8*>(SM + QTB_OFF + swz(16 + mrow, k0));
            #pragma unroll
            for (int nf = 0; nf < 4; ++nf) {
                dacc[0][nf] = __builtin_amdgcn_mfma_f32_16x16x32_bf16(a0, dB[ks & 3][nf], dacc[0][nf], 0, 0, 0);
                dacc[1][nf] = __builtin_amdgcn_mfma_f32_16x16x32_bf16(a1, dB[ks & 3][nf], dacc[1][nf], 0, 0, 0);
            }
            if (ks < 4) {
                #pragma unroll
                for (int nf = 0; nf < 4; ++nf)
                    dB[ks][nf] = *reinterpret_cast<const short8*>(
                        &wdh[(ebase + nf * 16) * 256 + (ks + 4) * 32 + kfo]);
            } else if (h < 7) {
                #pragma unroll
                for (int nf = 0; nf < 4; ++nf)
                    hB[ks - 4][nf] = *reinterpret_cast<const short8*>(
                        &WhH[((long)(h + 1) << 16) + (ebase + nf * 16) * 256 + (ks - 4) * 32 + kfo]);
            }
        }
        __syncthreads();   // qTb free for next h
    }
    // ---- epilogue: z = relu(dacc + bd) ----
    #pragma unroll
    for (int mt = 0; mt < 2; ++mt) {
        #pragma unroll
        for (int nf = 0; nf < 4; ++nf) {
            const int e = ebase + nf * 16;
            const float b = bd[e];
            #pragma unroll
            for (int reg = 0; reg < 4; ++reg)
                z[(rowbase + mt * 16 + kgrp * 4 + reg) * 256 + e] =
                    fmaxf(dacc[mt][nf][reg] + b, 0.0f);
        }
    }
    // ---- lsh decode -> int8 plane ----
    {
        signed char* lsh8 = (signed char*)(SM + LSH8_OFF);
        #pragma unroll
        for (int mt = 0; mt < 2; ++mt)
            #pragma unroll
            for (int nf = 0; nf < 4; ++nf) {
                const int e = ebase + nf * 16;
                #pragma unroll
                for (int reg = 0; reg < 4; ++reg) {
                    const int r = mt * 16 + kgrp * 4 + reg;
                    const int j = mt * 16 + nf * 4 + reg;
                    const unsigned p = (lshp[j >> 3] >> (4 * (j & 7))) & 15u;
                    lsh8[e * 32 + r] = (signed char)(2 * (int)p - 8);
                }
            }
    }
    __syncthreads();
    // ---- guard: exact ascending-k f32 chain; sign flips -> correction list ----
    {
        int n = *((int*)(SM + FCN_OFF));
        n = n < FLS_CAP ? n : FLS_CAP;
        for (int i = tid; i < n; i += 256) {
            const int ent = ((int*)(SM + FLS_OFF))[i];
            const int r = ent & 31, e = (ent >> 5) & 255, hh2 = (ent >> 13) & 7;
            const int fs = ((ent >> 16) & 1) ? 1 : -1;
            const float* xr = x + (rowbase + r) * 256;
            const float* wrow = WhT + (((long)hh2 << 8) + e) * 256;
            float acc = 0.0f;
            for (int k = 0; k < 256; k += 4) {
                float4 xv = *reinterpret_cast<const float4*>(xr + k);
                float4 wv = *reinterpret_cast<const float4*>(wrow + k);
                acc = fmaf(xv.x, wv.x, acc);
                acc = fmaf(xv.y, wv.y, acc);
                acc = fmaf(xv.z, wv.z, acc);
                acc = fmaf(xv.w, wv.w, acc);
            }
            const float pre = __fadd_rn(acc, bh[hh2 * 256 + e]);
            const int es = (pre > 0.0f) ? 1 : -1;
            if (es != fs) {
                int ci = atomicAdd((int*)(SM + CCN_OFF), 1);
                if (ci < CLS_CAP)
                    ((int*)(SM + CLS_OFF))[ci] = r | (e << 5) | ((es > 0 ? 1 : 0) << 13);
            }
        }
    }
    __syncthreads();
    if (tid == 0) {   // apply corrections serially (race-free byte RMW)
        signed char* lsh8 = (signed char*)(SM + LSH8_OFF);
        int cn = *((int*)(SM + CCN_OFF));
        cn = cn < CLS_CAP ? cn : CLS_CAP;
        for (int i = 0; i < cn; ++i) {
            const int ent = ((int*)(SM + CLS_OFF))[i];
            const int r = ent & 31, e = (ent >> 5) & 255;
            const int d = ((ent >> 13) & 1) ? 2 : -2;
            lsh8[e * 32 + r] = (signed char)(lsh8[e * 32 + r] + d);
        }
    }
    __syncthreads();
    // ---- tail: stable counting sort + simv (bit-exact, r9-verified) ----
    if (tid < 32) {
        const int r = tid;
        const signed char* lsh8 = (const signed char*)(SM + LSH8_OFF);
        const float* pe_over = (const float*)(SM + PE_OFF);
        const float* c_f = (const float*)(SM + CF_OFF);
        int* cw = (int*)(SM + CNT_OFF) + r * 16;
        for (int i = 0; i < 9; ++i) cw[i] = 0;
        for (int d = 0; d < 256; ++d) {
            int vv = (int)lsh8[d * 32 + r];
            cw[(vv + 8) >> 1] += 1;
        }
        int run = 0;
        for (int bin = 8; bin >= 0; --bin) { int c0 = cw[bin]; cw[bin] = run; run += c0; }
        float* valq = (float*)(SM + r * 1024);   // overlays dead XSH/QTB
        for (int d = 0; d < 256; ++d) {
            int vv = (int)lsh8[d * 32 + r];
            int bin = (vv + 8) >> 1;
            int j = cw[bin]++;
            valq[j] = __fadd_rn((float)vv, pe_over[d]);
        }
        float L0 = 0.f, L1 = 0.f, L2 = 0.f, L3 = 0.f,
              L4 = 0.f, L5 = 0.f, L6 = 0.f, L7 = 0.f;
        for (int i = 0; i < 256; i += 8) {
            L0 = fmaf(valq[i + 0], c_f[i + 0], L0);
            L1 = fmaf(valq[i + 1], c_f[i + 1], L1);
            L2 = fmaf(valq[i + 2], c_f[i + 2], L2);
            L3 = fmaf(valq[i + 3], c_f[i + 3], L3);
            L4 = fmaf(valq[i + 4], c_f[i + 4], L4);
            L5 = fmaf(valq[i + 5], c_f[i + 5], L5);
            L6 = fmaf(valq[i + 6], c_f[i + 6], L6);
            L7 = fmaf(valq[i + 7], c_f[i + 7], L7);
        }
        const float h0 = __fadd_rn(L0, L4);
        const float h1 = __fadd_rn(L1, L5);
        const float h2 = __fadd_rn(L2, L6);
        const float h3 = __fadd_rn(L3, L7);
        simv[rowbase + r] = __fadd_rn(__fadd_rn(h0, h2), __fadd_rn(h1, h3));
    }
}

// ---------------- K2: stable rank -> order ----------------
__global__ __launch_bounds__(256)
void k2_rank(const float* __restrict__ simv, int* __restrict__ order)
{
    __shared__ float s_l[4096];
    const int b = blockIdx.x >> 4;
    const int chunk = blockIdx.x & 15;
    const float* S = simv + (long)b * 4096;
    for (int i = threadIdx.x; i < 4096; i += 256) s_l[i] = S[i];
    __syncthreads();
    const int n = chunk * 256 + threadIdx.x;
    const float key = s_l[n];
    int cnt = 0;
    for (int m = 0; m < 4096; ++m) {
        float sm = s_l[m];
        cnt += (sm < key) ? 1 : ((sm == key && m < n) ? 1 : 0);
    }
    order[(long)b * 4096 + cnt] = n;
}

// ---------------- K3: value GEMM on gathered rows (bf16 MFMA) ----------------
__global__ __launch_bounds__(256, 3)
void k3_value(const float* __restrict__ z, const int* __restrict__ order,
              const unsigned short* __restrict__ WvT, const float* __restrict__ bv,
              float* __restrict__ v)
{
    __shared__ __align__(16) unsigned short ZB[32 * 256];   // swizzled bf16
    __shared__ int ord[32];
    const int tid = threadIdx.x;
    const long rowbase = (long)blockIdx.x * 32;
    const long bbase = (rowbase >> 12) << 12;
    const int wavei = tid >> 6, lane = tid & 63;
    const int mrow = lane & 15, kgrp = lane >> 4;
    const int ebase = wavei * 64 + mrow;
    const int kfo = kgrp * 8;

    if (tid < 32) ord[tid] = order[rowbase + tid];

    short8 vB[3][4];
    #pragma unroll
    for (int i = 0; i < 2; ++i)
        #pragma unroll
        for (int nf = 0; nf < 4; ++nf)
            vB[i][nf] = *reinterpret_cast<const short8*>(
                &WvT[(ebase + nf * 16) * 256 + i * 32 + kfo]);

    __syncthreads();   // ord visible
    {   // gather z rows (sorted order) -> bf16 LDS
        const int r = tid >> 3, kc = (tid & 7) * 32;
        const float* src = z + (bbase + ord[r]) * 256 + kc;
        unsigned short oh[32];
        #pragma unroll
        for (int i = 0; i < 32; i += 4) {
            float4 vv = *reinterpret_cast<const float4*>(src + i);
            oh[i + 0] = f2bf(vv.x); oh[i + 1] = f2bf(vv.y);
            oh[i + 2] = f2bf(vv.z); oh[i + 3] = f2bf(vv.w);
        }
        #pragma unroll
        for (int i = 0; i < 32; i += 8)
            *reinterpret_cast<short8*>((char*)ZB + swz(r, kc + i)) =
                *reinterpret_cast<short8*>(&oh[i]);
    }
    __syncthreads();

    f32x4 acc[2][4];
    #pragma unroll
    for (int mt = 0; mt < 2; ++mt)
        #pragma unroll
        for (int nf = 0; nf < 4; ++nf) acc[mt][nf] = (f32x4){0.f, 0.f, 0.f, 0.f};
    #pragma unroll
    for (int kt = 0; kt < 8; ++kt) {
        const int k0 = kt * 32 + kfo;
        short8 a0 = *reinterpret_cast<const short8*>((char*)ZB + swz(mrow, k0));
        short8 a1 = *reinterpret_cast<const short8*>((char*)ZB + swz(16 + mrow, k0));
        if (kt < 6) {
            #pragma unroll
            for (int nf = 0; nf < 4; ++nf)
                vB[(kt + 2) % 3][nf] = *reinterpret_cast<const short8*>(
                    &WvT[(ebase + nf * 16) * 256 + (kt + 2) * 32 + kfo]);
        }
        #pragma unroll
        for (int nf = 0; nf < 4; ++nf) {
            acc[0][nf] = __builtin_amdgcn_mfma_f32_16x16x32_bf16(a0, vB[kt % 3][nf], acc[0][nf], 0, 0, 0);
            acc[1][nf] = __builtin_amdgcn_mfma_f32_16x16x32_bf16(a1, vB[kt % 3][nf], acc[1][nf], 0, 0, 0);
        }
    }
    #pragma unroll
    for (int mt = 0; mt < 2; ++mt) {
        #pragma unroll
        for (int nf = 0; nf < 4; ++nf) {
            const int e = ebase + nf * 16;
            const float b = bv[e];
            #pragma unroll
            for (int reg = 0; reg < 4; ++reg)
                v[(rowbase + mt * 16 + kgrp * 4 + reg) * 256 + e] =
                    fmaxf(acc[mt][nf][reg] + b, 0.0f);
        }
    }
}

// ---------------- K4: windowed attention + residual + LayerNorm ----------------
__global__ __launch_bounds__(256)
void k4_attn_ln(const float* __restrict__ z, const float* __restrict__ v,
                const int* __restrict__ order, const float* __restrict__ x,
                const float* __restrict__ gamma, const float* __restrict__ beta,
                float* __restrict__ out)
{
    const int tid = threadIdx.x;
    const int wv = tid >> 6, lane = tid & 63;
    const long row = (long)blockIdx.x * 4 + wv;
    const int n = (int)(row & 4095);
    const long bbase = row - n;
    int start = n - 4;
    start = start < 0 ? 0 : start;
    start = start > (Nc - 9) ? (Nc - 9) : start;
    const int d0 = lane * 4;

    const int srcq = order[bbase + n];
    float4 q4 = *reinterpret_cast<const float4*>(&z[(bbase + srcq) * 256 + d0]);

    float t[9];
    #pragma unroll
    for (int w = 0; w < 9; ++w) {
        int srcm = order[bbase + start + w];
        float4 kv = *reinterpret_cast<const float4*>(&z[(bbase + srcm) * 256 + d0]);
        float p = q4.x * kv.x + q4.y * kv.y + q4.z * kv.z + q4.w * kv.w;
        #pragma unroll
        for (int off = 32; off > 0; off >>= 1) p += __shfl_xor(p, off);
        t[w] = p * 0.0625f;
    }
    float mx = t[0];
    #pragma unroll
    for (int w = 1; w < 9; ++w) mx = fmaxf(mx, t[w]);
    float pw[9], psum = 0.0f;
    #pragma unroll
    for (int w = 0; w < 9; ++w) { pw[w] = expf(t[w] - mx); psum += pw[w]; }
    const float pinv = 1.0f / psum;

    float4 a = make_float4(0.f, 0.f, 0.f, 0.f);
    #pragma unroll
    for (int w = 0; w < 9; ++w) {
        float4 vv = *reinterpret_cast<const float4*>(&v[(bbase + start + w) * 256 + d0]);
        float s = pw[w] * pinv;
        a.x = fmaf(vv.x, s, a.x);
        a.y = fmaf(vv.y, s, a.y);
        a.z = fmaf(vv.z, s, a.z);
        a.w = fmaf(vv.w, s, a.w);
    }
    float4 xv = *reinterpret_cast<const float4*>(&x[(bbase + n) * 256 + d0]);
    float4 y = make_float4(a.x + xv.x, a.y + xv.y, a.z + xv.z, a.w + xv.w);

    float s1 = y.x + y.y + y.z + y.w;
    float s2 = y.x * y.x + y.y * y.y + y.z * y.z + y.w * y.w;
    #pragma unroll
    for (int off = 32; off > 0; off >>= 1) {
        s1 += __shfl_xor(s1, off);
        s2 += __shfl_xor(s2, off);
    }
    const float mu = s1 * (1.0f / 256.0f);
    const float var = s2 * (1.0f / 256.0f) - mu * mu;
    const float istd = 1.0f / sqrtf(var + 0.001f);

    float4 g4 = *reinterpret_cast<const float4*>(&gamma[d0]);
    float4 b4 = *reinterpret_cast<const float4*>(&beta[d0]);
    float4 o;
    o.x = (y.x - mu) * istd * g4.x + b4.x;
    o.y = (y.y - mu) * istd * g4.y + b4.y;
    o.z = (y.z - mu) * istd * g4.z + b4.z;
    o.w = (y.w - mu) * istd * g4.w + b4.w;
    *reinterpret_cast<float4*>(&out[row * 256 + d0]) = o;
}

extern "C" void kernel_launch(void* const* d_in, const int* in_sizes, int n_in,
                              void* d_out, int out_size, void* d_ws, size_t ws_size,
                              hipStream_t stream)
{
    const float* x  = (const float*)d_in[0];
    const float* Wh = (const float*)d_in[1];
    const float* bh = (const float*)d_in[2];
    const float* Wd = (const float*)d_in[3];
    const float* bd = (const float*)d_in[4];
    const float* Wv = (const float*)d_in[5];
    const float* bv = (const float*)d_in[6];
    const float* g  = (const float*)d_in[7];
    const float* be = (const float*)d_in[8];
    float* out = (float*)d_out;

    char* ws = (char*)d_ws;
    float*          z     = (float*)ws;                       // 33554432 B
    float*          v     = (float*)(ws + 33554432);          // 33554432 B
    float*          simv  = (float*)(ws + 67108864);          // 131072 B
    int*            order = (int*)(ws + 67239936);            // 131072 B
    unsigned short* WdT   = (unsigned short*)(ws + 67371008); // 1048576 B
    unsigned short* WhH   = (unsigned short*)(ws + 68419584); // 1048576 B
    float*          WhT   = (float*)(ws + 69468160);          // 2097152 B
    unsigned short* WvT   = (unsigned short*)(ws + 71565312); // 131072 B

    const int rows = Bc * Nc;                                 // 32768
    k0_wdt<<<dim3(128), dim3(256), 0, stream>>>(Wd, WdT);
    k0_wht<<<dim3(128), dim3(256), 0, stream>>>(Wh, WhH, WhT);
    k0_wvt<<<dim3(16), dim3(256), 0, stream>>>(Wv, WvT);
    k1_head_down<<<dim3(rows / 32), dim3(256), 0, stream>>>(x, bh, WhT, WhH, WdT, bd, z, simv);
    k2_rank<<<dim3(Bc * 16), dim3(256), 0, stream>>>(simv, order);
    k3_value<<<dim3(rows / 32), dim3(256), 0, stream>>>(z, order, WvT, bv, v);
    k4_attn_ln<<<dim3(rows / 4), dim3(256), 0, stream>>>(z, v, order, x, g, be, out);
}

// Round 19
// 817.942 us; speedup vs baseline: 1.0409x; 1.0409x over previous
//
#include <hip/hip_runtime.h>

constexpr int Bc = 8, Nc = 4096;

using short8 = __attribute__((ext_vector_type(8))) short;
using f32x4  = __attribute__((ext_vector_type(4))) float;

static __device__ __forceinline__ unsigned short f2bf(float f) {
    unsigned u = __float_as_uint(f);
    u += 0x7fffu + ((u >> 16) & 1u);     // RNE
    return (unsigned short)(u >> 16);
}
// XOR-swizzled byte offset for a [32][256] ushort LDS plane (16B-access safe)
static __device__ __forceinline__ int swz(int r, int k) {
    return (r << 9) + ((k << 1) ^ ((r & 7) << 4));
}

#define GBIN_CAP 320
#define GUARD    0.012f

// ---------------- K0a: Wd [h][d][e] f32 -> WdT [h][e][d] bf16 ----------------
__global__ __launch_bounds__(256)
void k0_wdt(const float* __restrict__ Wd, unsigned short* __restrict__ WdT)
{
    __shared__ float tile[64][65];
    const int h  = blockIdx.x >> 4;
    const int t  = blockIdx.x & 15;
    const int kb = (t >> 2) * 64, eb = (t & 3) * 64;
    const int tid = threadIdx.x;
    {
        const int krow = tid >> 2, ec = (tid & 3) * 16;
        const float* src = Wd + h * 65536 + (kb + krow) * 256 + eb + ec;
        #pragma unroll
        for (int i = 0; i < 4; ++i) {
            float4 v = *reinterpret_cast<const float4*>(src + i * 4);
            tile[krow][ec + i * 4 + 0] = v.x;
            tile[krow][ec + i * 4 + 1] = v.y;
            tile[krow][ec + i * 4 + 2] = v.z;
            tile[krow][ec + i * 4 + 3] = v.w;
        }
    }
    __syncthreads();
    {
        const int erow = tid >> 2, dc = (tid & 3) * 16;
        unsigned short o[16];
        #pragma unroll
        for (int i = 0; i < 16; ++i) o[i] = f2bf(tile[dc + i][erow]);
        unsigned short* dst = WdT + h * 65536 + (eb + erow) * 256 + kb + dc;
        *reinterpret_cast<short8*>(dst)     = *reinterpret_cast<short8*>(&o[0]);
        *reinterpret_cast<short8*>(dst + 8) = *reinterpret_cast<short8*>(&o[8]);
    }
}

// ---------------- K0b: Wh [k][h][e] f32 -> WhH bf16 [h][e][k] + WhT f32 [h][e][k] ----------------
__global__ __launch_bounds__(256)
void k0_wht(const float* __restrict__ Wh, unsigned short* __restrict__ WhH,
            float* __restrict__ WhT)
{
    __shared__ float tile[64][65];
    const int h  = blockIdx.x >> 4;
    const int t  = blockIdx.x & 15;
    const int kb = (t >> 2) * 64, eb = (t & 3) * 64;
    const int tid = threadIdx.x;
    {
        const int krow = tid >> 2, ec = (tid & 3) * 16;
        const float* src = Wh + (kb + krow) * 2048 + h * 256 + eb + ec;
        #pragma unroll
        for (int i = 0; i < 4; ++i) {
            float4 v = *reinterpret_cast<const float4*>(src + i * 4);
            tile[krow][ec + i * 4 + 0] = v.x;
            tile[krow][ec + i * 4 + 1] = v.y;
            tile[krow][ec + i * 4 + 2] = v.z;
            tile[krow][ec + i * 4 + 3] = v.w;
        }
    }
    __syncthreads();
    {
        const int erow = tid >> 2, dc = (tid & 3) * 16;
        unsigned short o[16];
        float of[16];
        #pragma unroll
        for (int i = 0; i < 16; ++i) {
            of[i] = tile[dc + i][erow];
            o[i] = f2bf(of[i]);
        }
        const long base = (long)h * 65536 + (eb + erow) * 256 + kb + dc;
        *reinterpret_cast<short8*>(WhH + base)     = *reinterpret_cast<short8*>(&o[0]);
        *reinterpret_cast<short8*>(WhH + base + 8) = *reinterpret_cast<short8*>(&o[8]);
        #pragma unroll
        for (int i = 0; i < 16; i += 4)
            *reinterpret_cast<float4*>(WhT + base + i) = *reinterpret_cast<const float4*>(&of[i]);
    }
}

// ---------------- K0c: Wv [k][e] f32 -> WvT [e][k] bf16 ----------------
__global__ __launch_bounds__(256)
void k0_wvt(const float* __restrict__ Wv, unsigned short* __restrict__ WvT)
{
    __shared__ float tile[64][65];
    const int t  = blockIdx.x;
    const int kb = (t >> 2) * 64, eb = (t & 3) * 64;
    const int tid = threadIdx.x;
    {
        const int krow = tid >> 2, ec = (tid & 3) * 16;
        const float* src = Wv + (kb + krow) * 256 + eb + ec;
        #pragma unroll
        for (int i = 0; i < 4; ++i) {
            float4 v = *reinterpret_cast<const float4*>(src + i * 4);
            tile[krow][ec + i * 4 + 0] = v.x;
            tile[krow][ec + i * 4 + 1] = v.y;
            tile[krow][ec + i * 4 + 2] = v.z;
            tile[krow][ec + i * 4 + 3] = v.w;
        }
    }
    __syncthreads();
    {
        const int erow = tid >> 2, dc = (tid & 3) * 16;
        unsigned short o[16];
        #pragma unroll
        for (int i = 0; i < 16; ++i) o[i] = f2bf(tile[dc + i][erow]);
        unsigned short* dst = WvT + (eb + erow) * 256 + kb + dc;
        *reinterpret_cast<short8*>(dst)     = *reinterpret_cast<short8*>(&o[0]);
        *reinterpret_cast<short8*>(dst + 8) = *reinterpret_cast<short8*>(&o[8]);
    }
}

// ================= SPLIT PATH =================
// ---------------- K1a: head GEMM (one h per block), q bf16 + guard bins ----------------
__global__ __launch_bounds__(256, 3)
void k1a_head(const float* __restrict__ x, const float* __restrict__ bh,
              const unsigned short* __restrict__ WhH,
              unsigned short* __restrict__ q, int* __restrict__ gcnt, int* __restrict__ gls)
{
    __shared__ __align__(16) char SM[16384];   // x tile, then reused as q tile

    const int tid = threadIdx.x;
    const long rowbase = (long)blockIdx.x * 32;
    const int h = blockIdx.y;
    const int wavei = tid >> 6, lane = tid & 63;
    const int mrow = lane & 15, kgrp = lane >> 4;
    const int ebase = wavei * 64 + mrow;
    const int kfo = kgrp * 8;
    const unsigned short* whh = WhH + ((long)h << 16);

    short8 hB[4][4];
    #pragma unroll
    for (int i = 0; i < 4; ++i)
        #pragma unroll
        for (int nf = 0; nf < 4; ++nf)
            hB[i][nf] = *reinterpret_cast<const short8*>(
                &whh[(ebase + nf * 16) * 256 + i * 32 + kfo]);

    {   // x -> bf16 LDS (swizzled)
        const int r = tid >> 3, kc = (tid & 7) * 32;
        const float* src = x + (rowbase + r) * 256 + kc;
        unsigned short oh[32];
        #pragma unroll
        for (int i = 0; i < 32; i += 4) {
            float4 v = *reinterpret_cast<const float4*>(src + i);
            oh[i + 0] = f2bf(v.x); oh[i + 1] = f2bf(v.y);
            oh[i + 2] = f2bf(v.z); oh[i + 3] = f2bf(v.w);
        }
        #pragma unroll
        for (int i = 0; i < 32; i += 8)
            *reinterpret_cast<short8*>(SM + swz(r, kc + i)) =
                *reinterpret_cast<short8*>(&oh[i]);
    }
    __syncthreads();

    f32x4 hacc[2][4];
    #pragma unroll
    for (int mt = 0; mt < 2; ++mt)
        #pragma unroll
        for (int nf = 0; nf < 4; ++nf) hacc[mt][nf] = (f32x4){0.f, 0.f, 0.f, 0.f};
    #pragma unroll
    for (int kt = 0; kt < 8; ++kt) {
        const int k0 = kt * 32 + kfo;
        short8 a0 = *reinterpret_cast<const short8*>(SM + swz(mrow, k0));
        short8 a1 = *reinterpret_cast<const short8*>(SM + swz(16 + mrow, k0));
        #pragma unroll
        for (int nf = 0; nf < 4; ++nf) {
            hacc[0][nf] = __builtin_amdgcn_mfma_f32_16x16x32_bf16(a0, hB[kt & 3][nf], hacc[0][nf], 0, 0, 0);
            hacc[1][nf] = __builtin_amdgcn_mfma_f32_16x16x32_bf16(a1, hB[kt & 3][nf], hacc[1][nf], 0, 0, 0);
        }
        if (kt < 4) {
            #pragma unroll
            for (int nf = 0; nf < 4; ++nf)
                hB[kt][nf] = *reinterpret_cast<const short8*>(
                    &whh[(ebase + nf * 16) * 256 + (kt + 4) * 32 + kfo]);
        }
    }
    float bias[4];
    #pragma unroll
    for (int nf = 0; nf < 4; ++nf) bias[nf] = bh[(h << 8) + ebase + nf * 16];
    __syncthreads();   // all waves done reading x tile -> reuse as q tile
    const int bin = (int)blockIdx.x * 8 + h;
    #pragma unroll
    for (int mt = 0; mt < 2; ++mt) {
        #pragma unroll
        for (int nf = 0; nf < 4; ++nf) {
            const int e = ebase + nf * 16;
            #pragma unroll
            for (int reg = 0; reg < 4; ++reg) {
                const int r = mt * 16 + kgrp * 4 + reg;
                const float pre = __fadd_rn(hacc[mt][nf][reg], bias[nf]);
                if (fabsf(pre) < GUARD) {
                    int idx = atomicAdd(&gcnt[bin], 1);
                    if (idx < GBIN_CAP)
                        gls[bin * GBIN_CAP + idx] =
                            r | (e << 5) | ((pre > 0.0f ? 1 : 0) << 13);
                }
                *reinterpret_cast<unsigned short*>(SM + swz(r, e)) =
                    f2bf(fmaxf(pre, 0.0f));
            }
        }
    }
    __syncthreads();
    {   // coalesced q store
        const int r = tid >> 3, ec = (tid & 7) * 32;
        unsigned short* dst = q + (rowbase + r) * 2048 + (h << 8) + ec;
        #pragma unroll
        for (int i = 0; i < 4; ++i)
            *reinterpret_cast<short8*>(dst + i * 8) =
                *reinterpret_cast<short8*>(SM + swz(r, ec + i * 8));
    }
}

// ---------------- K1b: down GEMM z = q[32768,2048] x WdFlat[2048,256] ----------------
__global__ __launch_bounds__(256, 3)
void k1b_down(const unsigned short* __restrict__ q,
              const unsigned short* __restrict__ WdT, const float* __restrict__ bd,
              float* __restrict__ z)
{
    __shared__ __align__(16) char SM[16384];   // A tile (32 rows x 256 k bf16 swz)

    const int tid = threadIdx.x;
    const long rowbase = (long)blockIdx.x * 32;
    const int wavei = tid >> 6, lane = tid & 63;
    const int mrow = lane & 15, kgrp = lane >> 4;
    const int ebase = wavei * 64 + mrow;
    const int kfo = kgrp * 8;

    short8 dB[4][4];
    #pragma unroll
    for (int i = 0; i < 4; ++i)
        #pragma unroll
        for (int nf = 0; nf < 4; ++nf)
            dB[i][nf] = *reinterpret_cast<const short8*>(
                &WdT[(ebase + nf * 16) * 256 + i * 32 + kfo]);

    f32x4 dacc[2][4];
    #pragma unroll
    for (int mt = 0; mt < 2; ++mt)
        #pragma unroll
        for (int nf = 0; nf < 4; ++nf) dacc[mt][nf] = (f32x4){0.f, 0.f, 0.f, 0.f};

    for (int kc = 0; kc < 8; ++kc) {
        const unsigned short* wdh = WdT + ((long)kc << 16);
        {   // stage A chunk: rows 32 x k 256 (k = kc*256 ..)
            const int r = tid >> 3, kb2 = (tid & 7) * 32;
            const unsigned short* src = q + (rowbase + r) * 2048 + (kc << 8) + kb2;
            short8 t0 = *reinterpret_cast<const short8*>(src);
            short8 t1 = *reinterpret_cast<const short8*>(src + 8);
            short8 t2 = *reinterpret_cast<const short8*>(src + 16);
            short8 t3 = *reinterpret_cast<const short8*>(src + 24);
            *reinterpret_cast<short8*>(SM + swz(r, kb2))      = t0;
            *reinterpret_cast<short8*>(SM + swz(r, kb2 + 8))  = t1;
            *reinterpret_cast<short8*>(SM + swz(r, kb2 + 16)) = t2;
            *reinterpret_cast<short8*>(SM + swz(r, kb2 + 24)) = t3;
        }
        __syncthreads();
        #pragma unroll
        for (int ks = 0; ks < 8; ++ks) {
            const int k0 = ks * 32 + kfo;
            short8 a0 = *reinterpret_cast<const short8*>(SM + swz(mrow, k0));
            short8 a1 = *reinterpret_cast<const short8*>(SM + swz(16 + mrow, k0));
            #pragma unroll
            for (int nf = 0; nf < 4; ++nf) {
                dacc[0][nf] = __builtin_amdgcn_mfma_f32_16x16x32_bf16(a0, dB[ks & 3][nf], dacc[0][nf], 0, 0, 0);
                dacc[1][nf] = __builtin_amdgcn_mfma_f32_16x16x32_bf16(a1, dB[ks & 3][nf], dacc[1][nf], 0, 0, 0);
            }
            if (ks < 4) {
                #pragma unroll
                for (int nf = 0; nf < 4; ++nf)
                    dB[ks][nf] = *reinterpret_cast<const short8*>(
                        &wdh[(ebase + nf * 16) * 256 + (ks + 4) * 32 + kfo]);
            } else if (kc < 7) {
                #pragma unroll
                for (int nf = 0; nf < 4; ++nf)
                    dB[ks - 4][nf] = *reinterpret_cast<const short8*>(
                        &WdT[((long)(kc + 1) << 16) + (ebase + nf * 16) * 256 + (ks - 4) * 32 + kfo]);
            }
        }
        __syncthreads();
    }
    #pragma unroll
    for (int mt = 0; mt < 2; ++mt) {
        #pragma unroll
        for (int nf = 0; nf < 4; ++nf) {
            const int e = ebase + nf * 16;
            const float b = bd[e];
            #pragma unroll
            for (int reg = 0; reg < 4; ++reg)
                z[(rowbase + mt * 16 + kgrp * 4 + reg) * 256 + e] =
                    fmaxf(dacc[mt][nf][reg] + b, 0.0f);
        }
    }
}

// K1R LDS map
#define R_VALQ 0       // 32KB (also lsh accumulation is in regs)
#define R_LSH8 32768   // s8[256e][32r] 8KB
#define R_PE   40960
#define R_CF   41984
#define R_CNT  43008   // int[32][16]
#define R_CCN  45056
#define R_CLS  45060   // int[128]
#define R_CLS_CAP 128

// ---------------- K1R: lsh from q signs + guard fixes + counting sort + simv ----------------
__global__ __launch_bounds__(256, 2)
void k1r_lsh_simv(const unsigned short* __restrict__ q, const float* __restrict__ x,
                  const float* __restrict__ WhT, const float* __restrict__ bh,
                  const int* __restrict__ gcnt, const int* __restrict__ gls,
                  float* __restrict__ simv)
{
    __shared__ __align__(16) char SM[45576];
    const int tid = threadIdx.x;
    const long rowbase = (long)blockIdx.x * 32;

    {   // XLA:CPU twin tables (CR libm via f64-round)
        const int d = tid;
        const float u = -((float)d * 0.00390625f);
        const float freq = (float)pow(10.0, (double)u);
        const float pe = (d & 1) ? (float)sin((double)freq)
                                 : (float)cos((double)freq);
        ((float*)(SM + R_PE))[d] = __fdiv_rn(pe, 0.4f);
        ((float*)(SM + R_CF))[d] = __fmul_rn(0.4f, (float)pow((double)0.6f, (double)d));
    }
    if (tid == 0) *(int*)(SM + R_CCN) = 0;
    {   // lsh: sum of fast signs over h (q bf16 > 0 <=> fast pre > 0)
        const int r = tid >> 3, ec = (tid & 7) * 32;
        int acc[32];
        #pragma unroll
        for (int j = 0; j < 32; ++j) acc[j] = 0;
        for (int h = 0; h < 8; ++h) {
            const unsigned short* src = q + (rowbase + r) * 2048 + (h << 8) + ec;
            #pragma unroll
            for (int i = 0; i < 4; ++i) {
                short8 v8 = *reinterpret_cast<const short8*>(src + i * 8);
                #pragma unroll
                for (int j = 0; j < 8; ++j)
                    acc[i * 8 + j] += ((unsigned short)v8[j] != 0) ? 1 : -1;
            }
        }
        signed char* lsh8 = (signed char*)(SM + R_LSH8);
        #pragma unroll
        for (int j = 0; j < 32; ++j)
            lsh8[(ec + j) * 32 + r] = (signed char)acc[j];
    }
    __syncthreads();
    // guard fixes: exact ascending-k f32 chain (r9-verified semantics)
    for (int h = 0; h < 8; ++h) {
        const int bin = (int)blockIdx.x * 8 + h;
        int n = gcnt[bin];
        n = n < GBIN_CAP ? n : GBIN_CAP;
        for (int i = tid; i < n; i += 256) {
            const int ent = gls[bin * GBIN_CAP + i];
            const int r = ent & 31, e = (ent >> 5) & 255;
            const int fs = ((ent >> 13) & 1) ? 1 : -1;
            const float* xr = x + (rowbase + r) * 256;
            const float* wrow = WhT + (((long)h << 8) + e) * 256;
            float acc = 0.0f;
            for (int k = 0; k < 256; k += 4) {
                float4 xv = *reinterpret_cast<const float4*>(xr + k);
                float4 wv = *reinterpret_cast<const float4*>(wrow + k);
                acc = fmaf(xv.x, wv.x, acc);
                acc = fmaf(xv.y, wv.y, acc);
                acc = fmaf(xv.z, wv.z, acc);
                acc = fmaf(xv.w, wv.w, acc);
            }
            const float pre = __fadd_rn(acc, bh[h * 256 + e]);
            const int es = (pre > 0.0f) ? 1 : -1;
            if (es != fs) {
                int ci = atomicAdd((int*)(SM + R_CCN), 1);
                if (ci < R_CLS_CAP)
                    ((int*)(SM + R_CLS))[ci] = r | (e << 5) | ((es > 0 ? 1 : 0) << 13);
            }
        }
    }
    __syncthreads();
    if (tid == 0) {
        signed char* lsh8 = (signed char*)(SM + R_LSH8);
        int cn = *(int*)(SM + R_CCN);
        cn = cn < R_CLS_CAP ? cn : R_CLS_CAP;
        for (int i = 0; i < cn; ++i) {
            const int ent = ((int*)(SM + R_CLS))[i];
            const int r = ent & 31, e = (ent >> 5) & 255;
            const int d = ((ent >> 13) & 1) ? 2 : -2;
            lsh8[e * 32 + r] = (signed char)(lsh8[e * 32 + r] + d);
        }
    }
    __syncthreads();
    if (tid < 32) {   // stable counting sort + simv (bit-exact, r9-verified)
        const int r = tid;
        const signed char* lsh8 = (const signed char*)(SM + R_LSH8);
        const float* pe_over = (const float*)(SM + R_PE);
        const float* c_f = (const float*)(SM + R_CF);
        int* cw = (int*)(SM + R_CNT) + r * 16;
        for (int i = 0; i < 9; ++i) cw[i] = 0;
        for (int d = 0; d < 256; ++d) {
            int vv = (int)lsh8[d * 32 + r];
            cw[(vv + 8) >> 1] += 1;
        }
        int run = 0;
        for (int bin = 8; bin >= 0; --bin) { int c0 = cw[bin]; cw[bin] = run; run += c0; }
        float* valq = (float*)(SM + R_VALQ + r * 1024);
        for (int d = 0; d < 256; ++d) {
            int vv = (int)lsh8[d * 32 + r];
            int bin = (vv + 8) >> 1;
            int j = cw[bin]++;
            valq[j] = __fadd_rn((float)vv, pe_over[d]);
        }
        float L0 = 0.f, L1 = 0.f, L2 = 0.f, L3 = 0.f,
              L4 = 0.f, L5 = 0.f, L6 = 0.f, L7 = 0.f;
        for (int i = 0; i < 256; i += 8) {
            L0 = fmaf(valq[i + 0], c_f[i + 0], L0);
            L1 = fmaf(valq[i + 1], c_f[i + 1], L1);
            L2 = fmaf(valq[i + 2], c_f[i + 2], L2);
            L3 = fmaf(valq[i + 3], c_f[i + 3], L3);
            L4 = fmaf(valq[i + 4], c_f[i + 4], L4);
            L5 = fmaf(valq[i + 5], c_f[i + 5], L5);
            L6 = fmaf(valq[i + 6], c_f[i + 6], L6);
            L7 = fmaf(valq[i + 7], c_f[i + 7], L7);
        }
        const float h0 = __fadd_rn(L0, L4);
        const float h1 = __fadd_rn(L1, L5);
        const float h2 = __fadd_rn(L2, L6);
        const float h3 = __fadd_rn(L3, L7);
        simv[rowbase + r] = __fadd_rn(__fadd_rn(h0, h2), __fadd_rn(h1, h3));
    }
}

// ================= FALLBACK (r14 fused kernel, best proven) =================
#define XSH_OFF  0
#define QTB_OFF  16384
#define LSH8_OFF 32768
#define PE_OFF   40960
#define CF_OFF   41984
#define CNT_OFF  43008
#define FCN_OFF  45056
#define CCN_OFF  45060
#define FLS_OFF  45064
#define CLS_OFF  49160
#define FLS_CAP  1024
#define CLS_CAP  96

__global__ __launch_bounds__(256, 3)
void k1_fused(const float* __restrict__ x,
              const float* __restrict__ bh,
              const float* __restrict__ WhT,
              const unsigned short* __restrict__ WhH,
              const unsigned short* __restrict__ WdT, const float* __restrict__ bd,
              float* __restrict__ z, float* __restrict__ simv)
{
    __shared__ __align__(16) char SM[49600];
    const int tid = threadIdx.x;
    const long rowbase = (long)blockIdx.x * 32;
    const int wavei = tid >> 6, lane = tid & 63;
    const int mrow = lane & 15, kgrp = lane >> 4;
    const int ebase = wavei * 64 + mrow;
    const int kfo = kgrp * 8;

    short8 hB[3][4], dB[3][4];
    #pragma unroll
    for (int i = 0; i < 2; ++i)
        #pragma unroll
        for (int nf = 0; nf < 4; ++nf)
            hB[i][nf] = *reinterpret_cast<const short8*>(
                &WhH[(ebase + nf * 16) * 256 + i * 32 + kfo]);
    {
        const int d = tid;
        const float u = -((float)d * 0.00390625f);
        const float freq = (float)pow(10.0, (double)u);
        const float pe = (d & 1) ? (float)sin((double)freq)
                                 : (float)cos((double)freq);
        ((float*)(SM + PE_OFF))[d] = __fdiv_rn(pe, 0.4f);
        ((float*)(SM + CF_OFF))[d] = __fmul_rn(0.4f, (float)pow((double)0.6f, (double)d));
    }
    if (tid == 0) { *(int*)(SM + FCN_OFF) = 0; *(int*)(SM + CCN_OFF) = 0; }
    {
        const int r = tid >> 3, kc = (tid & 7) * 32;
        const float* src = x + (rowbase + r) * 256 + kc;
        unsigned short oh[32];
        #pragma unroll
        for (int i = 0; i < 32; i += 4) {
            float4 v = *reinterpret_cast<const float4*>(src + i);
            oh[i + 0] = f2bf(v.x); oh[i + 1] = f2bf(v.y);
            oh[i + 2] = f2bf(v.z); oh[i + 3] = f2bf(v.w);
        }
        #pragma unroll
        for (int i = 0; i < 32; i += 8)
            *reinterpret_cast<short8*>(SM + XSH_OFF + swz(r, kc + i)) =
                *reinterpret_cast<short8*>(&oh[i]);
    }
    unsigned lshp[4] = {0u, 0u, 0u, 0u};
    f32x4 dacc[2][4];
    #pragma unroll
    for (int mt = 0; mt < 2; ++mt)
        #pragma unroll
        for (int nf = 0; nf < 4; ++nf) dacc[mt][nf] = (f32x4){0.f, 0.f, 0.f, 0.f};
    __syncthreads();
    for (int h = 0; h < 8; ++h) {
        const unsigned short* whh = WhH + ((long)h << 16);
        const unsigned short* wdh = WdT + ((long)h << 16);
        float bias[4];
        #pragma unroll
        for (int nf = 0; nf < 4; ++nf) bias[nf] = bh[(h << 8) + ebase + nf * 16];
        f32x4 hacc[2][4];
        #pragma unroll
        for (int mt = 0; mt < 2; ++mt)
            #pragma unroll
            for (int nf = 0; nf < 4; ++nf) hacc[mt][nf] = (f32x4){0.f, 0.f, 0.f, 0.f};
        #pragma unroll
        for (int kt = 0; kt < 8; ++kt) {
            const int k0 = kt * 32 + kfo;
            short8 a0 = *reinterpret_cast<const short8*>(SM + XSH_OFF + swz(mrow, k0));
            short8 a1 = *reinterpret_cast<const short8*>(SM + XSH_OFF + swz(16 + mrow, k0));
            if (kt < 6) {
                #pragma unroll
                for (int nf = 0; nf < 4; ++nf)
                    hB[(kt + 2) % 3][nf] = *reinterpret_cast<const short8*>(
                        &whh[(ebase + nf * 16) * 256 + (kt + 2) * 32 + kfo]);
            }
            #pragma unroll
            for (int nf = 0; nf < 4; ++nf) {
                hacc[0][nf] = __builtin_amdgcn_mfma_f32_16x16x32_bf16(a0, hB[kt % 3][nf], hacc[0][nf], 0, 0, 0);
                hacc[1][nf] = __builtin_amdgcn_mfma_f32_16x16x32_bf16(a1, hB[kt % 3][nf], hacc[1][nf], 0, 0, 0);
            }
        }
        #pragma unroll
        for (int i = 0; i < 2; ++i)
            #pragma unroll
            for (int nf = 0; nf < 4; ++nf)
                dB[i][nf] = *reinterpret_cast<const short8*>(
                    &wdh[(ebase + nf * 16) * 256 + i * 32 + kfo]);
        #pragma unroll
        for (int mt = 0; mt < 2; ++mt) {
            #pragma unroll
            for (int nf = 0; nf < 4; ++nf) {
                const int e = ebase + nf * 16;
                #pragma unroll
                for (int reg = 0; reg < 4; ++reg) {
                    const int r = mt * 16 + kgrp * 4 + reg;
                    const float pre = __fadd_rn(hacc[mt][nf][reg], bias[nf]);
                    const unsigned pos = (pre > 0.0f) ? 1u : 0u;
                    const int j = mt * 16 + nf * 4 + reg;
                    lshp[j >> 3] += pos << (4 * (j & 7));
                    if (fabsf(pre) < GUARD) {
                        int idx = atomicAdd((int*)(SM + FCN_OFF), 1);
                        if (idx < FLS_CAP)
                            ((int*)(SM + FLS_OFF))[idx] =
                                r | (e << 5) | (h << 13) | ((int)pos << 16);
                    }
                    *reinterpret_cast<unsigned short*>(SM + QTB_OFF + swz(r, e)) =
                        f2bf(fmaxf(pre, 0.0f));
                }
            }
        }
        __syncthreads();
        #pragma unroll
        for (int ks = 0; ks < 8; ++ks) {
            const int k0 = ks * 32 + kfo;
            short8 a0 = *reinterpret_cast<const short8*>(SM + QTB_OFF + swz(mrow, k0));
            short8 a1 = *reinterpret_cast<const short8*>(SM + QTB_OFF + swz(16 + mrow, k0));
            if (ks < 6) {
                #pragma unroll
                for (int nf = 0; nf < 4; ++nf)
                    dB[(ks + 2) % 3][nf] = *reinterpret_cast<const short8*>(
                        &wdh[(ebase + nf * 16) * 256 + (ks + 2) * 32 + kfo]);
            } else if (h < 7) {
                const int i = ks - 6;
                #pragma unroll
                for (int nf = 0; nf < 4; ++nf)
                    hB[i][nf] = *reinterpret_cast<const short8*>(
                        &WhH[((long)(h + 1) << 16) + (ebase + nf * 16) * 256 + i * 32 + kfo]);
            }
            #pragma unroll
            for (int nf = 0; nf < 4; ++nf) {
                dacc[0][nf] = __builtin_amdgcn_mfma_f32_16x16x32_bf16(a0, dB[ks % 3][nf], dacc[0][nf], 0, 0, 0);
                dacc[1][nf] = __builtin_amdgcn_mfma_f32_16x16x32_bf16(a1, dB[ks % 3][nf], dacc[1][nf], 0, 0, 0);
            }
        }
        __syncthreads();
    }
    #pragma unroll
    for (int mt = 0; mt < 2; ++mt) {
        #pragma unroll
        for (int nf = 0; nf < 4; ++nf) {
            const int e = ebase + nf * 16;
            const float b = bd[e];
            #pragma unroll
            for (int reg = 0; reg < 4; ++reg)
                z[(rowbase + mt * 16 + kgrp * 4 + reg) * 256 + e] =
                    fmaxf(dacc[mt][nf][reg] + b, 0.0f);
        }
    }
    {
        signed char* lsh8 = (signed char*)(SM + LSH8_OFF);
        #pragma unroll
        for (int mt = 0; mt < 2; ++mt)
            #pragma unroll
            for (int nf = 0; nf < 4; ++nf) {
                const int e = ebase + nf * 16;
                #pragma unroll
                for (int reg = 0; reg < 4; ++reg) {
                    const int r = mt * 16 + kgrp * 4 + reg;
                    const int j = mt * 16 + nf * 4 + reg;
                    const unsigned p = (lshp[j >> 3] >> (4 * (j & 7))) & 15u;
                    lsh8[e * 32 + r] = (signed char)(2 * (int)p - 8);
                }
            }
    }
    __syncthreads();
    {
        int n = *((int*)(SM + FCN_OFF));
        n = n < FLS_CAP ? n : FLS_CAP;
        for (int i = tid; i < n; i += 256) {
            const int ent = ((int*)(SM + FLS_OFF))[i];
            const int r = ent & 31, e = (ent >> 5) & 255, hh2 = (ent >> 13) & 7;
            const int fs = ((ent >> 16) & 1) ? 1 : -1;
            const float* xr = x + (rowbase + r) * 256;
            const float* wrow = WhT + (((long)hh2 << 8) + e) * 256;
            float acc = 0.0f;
            for (int k = 0; k < 256; k += 4) {
                float4 xv = *reinterpret_cast<const float4*>(xr + k);
                float4 wv = *reinterpret_cast<const float4*>(wrow + k);
                acc = fmaf(xv.x, wv.x, acc);
                acc = fmaf(xv.y, wv.y, acc);
                acc = fmaf(xv.z, wv.z, acc);
                acc = fmaf(xv.w, wv.w, acc);
            }
            const float pre = __fadd_rn(acc, bh[hh2 * 256 + e]);
            const int es = (pre > 0.0f) ? 1 : -1;
            if (es != fs) {
                int ci = atomicAdd((int*)(SM + CCN_OFF), 1);
                if (ci < CLS_CAP)
                    ((int*)(SM + CLS_OFF))[ci] = r | (e << 5) | ((es > 0 ? 1 : 0) << 13);
            }
        }
    }
    __syncthreads();
    if (tid == 0) {
        signed char* lsh8 = (signed char*)(SM + LSH8_OFF);
        int cn = *((int*)(SM + CCN_OFF));
        cn = cn < CLS_CAP ? cn : CLS_CAP;
        for (int i = 0; i < cn; ++i) {
            const int ent = ((int*)(SM + CLS_OFF))[i];
            const int r = ent & 31, e = (ent >> 5) & 255;
            const int d = ((ent >> 13) & 1) ? 2 : -2;
            lsh8[e * 32 + r] = (signed char)(lsh8[e * 32 + r] + d);
        }
    }
    __syncthreads();
    if (tid < 32) {
        const int r = tid;
        const signed char* lsh8 = (const signed char*)(SM + LSH8_OFF);
        const float* pe_over = (const float*)(SM + PE_OFF);
        const float* c_f = (const float*)(SM + CF_OFF);
        int* cw = (int*)(SM + CNT_OFF) + r * 16;
        for (int i = 0; i < 9; ++i) cw[i] = 0;
        for (int d = 0; d < 256; ++d) {
            int vv = (int)lsh8[d * 32 + r];
            cw[(vv + 8) >> 1] += 1;
        }
        int run = 0;
        for (int bin = 8; bin >= 0; --bin) { int c0 = cw[bin]; cw[bin] = run; run += c0; }
        float* valq = (float*)(SM + r * 1024);
        for (int d = 0; d < 256; ++d) {
            int vv = (int)lsh8[d * 32 + r];
            int bin = (vv + 8) >> 1;
            int j = cw[bin]++;
            valq[j] = __fadd_rn((float)vv, pe_over[d]);
        }
        float L0 = 0.f, L1 = 0.f, L2 = 0.f, L3 = 0.f,
              L4 = 0.f, L5 = 0.f, L6 = 0.f, L7 = 0.f;
        for (int i = 0; i < 256; i += 8) {
            L0 = fmaf(valq[i + 0], c_f[i + 0], L0);
            L1 = fmaf(valq[i + 1], c_f[i + 1], L1);
            L2 = fmaf(valq[i + 2], c_f[i + 2], L2);
            L3 = fmaf(valq[i + 3], c_f[i + 3], L3);
            L4 = fmaf(valq[i + 4], c_f[i + 4], L4);
            L5 = fmaf(valq[i + 5], c_f[i + 5], L5);
            L6 = fmaf(valq[i + 6], c_f[i + 6], L6);
            L7 = fmaf(valq[i + 7], c_f[i + 7], L7);
        }
        const float h0 = __fadd_rn(L0, L4);
        const float h1 = __fadd_rn(L1, L5);
        const float h2 = __fadd_rn(L2, L6);
        const float h3 = __fadd_rn(L3, L7);
        simv[rowbase + r] = __fadd_rn(__fadd_rn(h0, h2), __fadd_rn(h1, h3));
    }
}

// ---------------- K2: stable rank -> order ----------------
__global__ __launch_bounds__(256)
void k2_rank(const float* __restrict__ simv, int* __restrict__ order)
{
    __shared__ float s_l[4096];
    const int b = blockIdx.x >> 4;
    const int chunk = blockIdx.x & 15;
    const float* S = simv + (long)b * 4096;
    for (int i = threadIdx.x; i < 4096; i += 256) s_l[i] = S[i];
    __syncthreads();
    const int n = chunk * 256 + threadIdx.x;
    const float key = s_l[n];
    int cnt = 0;
    for (int m = 0; m < 4096; ++m) {
        float sm = s_l[m];
        cnt += (sm < key) ? 1 : ((sm == key && m < n) ? 1 : 0);
    }
    order[(long)b * 4096 + cnt] = n;
}

// ---------------- K3: value GEMM on gathered rows (bf16 MFMA) ----------------
__global__ __launch_bounds__(256, 3)
void k3_value(const float* __restrict__ z, const int* __restrict__ order,
              const unsigned short* __restrict__ WvT, const float* __restrict__ bv,
              float* __restrict__ v)
{
    __shared__ __align__(16) unsigned short ZB[32 * 256];
    __shared__ int ord[32];
    const int tid = threadIdx.x;
    const long rowbase = (long)blockIdx.x * 32;
    const long bbase = (rowbase >> 12) << 12;
    const int wavei = tid >> 6, lane = tid & 63;
    const int mrow = lane & 15, kgrp = lane >> 4;
    const int ebase = wavei * 64 + mrow;
    const int kfo = kgrp * 8;

    if (tid < 32) ord[tid] = order[rowbase + tid];

    short8 vB[3][4];
    #pragma unroll
    for (int i = 0; i < 2; ++i)
        #pragma unroll
        for (int nf = 0; nf < 4; ++nf)
            vB[i][nf] = *reinterpret_cast<const short8*>(
                &WvT[(ebase + nf * 16) * 256 + i * 32 + kfo]);

    __syncthreads();
    {
        const int r = tid >> 3, kc = (tid & 7) * 32;
        const float* src = z + (bbase + ord[r]) * 256 + kc;
        unsigned short oh[32];
        #pragma unroll
        for (int i = 0; i < 32; i += 4) {
            float4 vv = *reinterpret_cast<const float4*>(src + i);
            oh[i + 0] = f2bf(vv.x); oh[i + 1] = f2bf(vv.y);
            oh[i + 2] = f2bf(vv.z); oh[i + 3] = f2bf(vv.w);
        }
        #pragma unroll
        for (int i = 0; i < 32; i += 8)
            *reinterpret_cast<short8*>((char*)ZB + swz(r, kc + i)) =
                *reinterpret_cast<short8*>(&oh[i]);
    }
    __syncthreads();

    f32x4 acc[2][4];
    #pragma unroll
    for (int mt = 0; mt < 2; ++mt)
        #pragma unroll
        for (int nf = 0; nf < 4; ++nf) acc[mt][nf] = (f32x4){0.f, 0.f, 0.f, 0.f};
    #pragma unroll
    for (int kt = 0; kt < 8; ++kt) {
        const int k0 = kt * 32 + kfo;
        short8 a0 = *reinterpret_cast<const short8*>((char*)ZB + swz(mrow, k0));
        short8 a1 = *reinterpret_cast<const short8*>((char*)ZB + swz(16 + mrow, k0));
        if (kt < 6) {
            #pragma unroll
            for (int nf = 0; nf < 4; ++nf)
                vB[(kt + 2) % 3][nf] = *reinterpret_cast<const short8*>(
                    &WvT[(ebase + nf * 16) * 256 + (kt + 2) * 32 + kfo]);
        }
        #pragma unroll
        for (int nf = 0; nf < 4; ++nf) {
            acc[0][nf] = __builtin_amdgcn_mfma_f32_16x16x32_bf16(a0, vB[kt % 3][nf], acc[0][nf], 0, 0, 0);
            acc[1][nf] = __builtin_amdgcn_mfma_f32_16x16x32_bf16(a1, vB[kt % 3][nf], acc[1][nf], 0, 0, 0);
        }
    }
    #pragma unroll
    for (int mt = 0; mt < 2; ++mt) {
        #pragma unroll
        for (int nf = 0; nf < 4; ++nf) {
            const int e = ebase + nf * 16;
            const float b = bv[e];
            #pragma unroll
            for (int reg = 0; reg < 4; ++reg)
                v[(rowbase + mt * 16 + kgrp * 4 + reg) * 256 + e] =
                    fmaxf(acc[mt][nf][reg] + b, 0.0f);
        }
    }
}

// ---------------- K4: windowed attention + residual + LayerNorm ----------------
__global__ __launch_bounds__(256)
void k4_attn_ln(const float* __restrict__ z, const float* __restrict__ v,
                const int* __restrict__ order, const float* __restrict__ x,
                const float* __restrict__ gamma, const float* __restrict__ beta,
                float* __restrict__ out)
{
    const int tid = threadIdx.x;
    const int wv = tid >> 6, lane = tid & 63;
    const long row = (long)blockIdx.x * 4 + wv;
    const int n = (int)(row & 4095);
    const long bbase = row - n;
    int start = n - 4;
    start = start < 0 ? 0 : start;
    start = start > (Nc - 9) ? (Nc - 9) : start;
    const int d0 = lane * 4;

    const int srcq = order[bbase + n];
    float4 q4 = *reinterpret_cast<const float4*>(&z[(bbase + srcq) * 256 + d0]);

    float t[9];
    #pragma unroll
    for (int w = 0; w < 9; ++w) {
        int srcm = order[bbase + start + w];
        float4 kv = *reinterpret_cast<const float4*>(&z[(bbase + srcm) * 256 + d0]);
        float p = q4.x * kv.x + q4.y * kv.y + q4.z * kv.z + q4.w * kv.w;
        #pragma unroll
        for (int off = 32; off > 0; off >>= 1) p += __shfl_xor(p, off);
        t[w] = p * 0.0625f;
    }
    float mx = t[0];
    #pragma unroll
    for (int w = 1; w < 9; ++w) mx = fmaxf(mx, t[w]);
    float pw[9], psum = 0.0f;
    #pragma unroll
    for (int w = 0; w < 9; ++w) { pw[w] = expf(t[w] - mx); psum += pw[w]; }
    const float pinv = 1.0f / psum;

    float4 a = make_float4(0.f, 0.f, 0.f, 0.f);
    #pragma unroll
    for (int w = 0; w < 9; ++w) {
        float4 vv = *reinterpret_cast<const float4*>(&v[(bbase + start + w) * 256 + d0]);
        float s = pw[w] * pinv;
        a.x = fmaf(vv.x, s, a.x);
        a.y = fmaf(vv.y, s, a.y);
        a.z = fmaf(vv.z, s, a.z);
        a.w = fmaf(vv.w, s, a.w);
    }
    float4 xv = *reinterpret_cast<const float4*>(&x[(bbase + n) * 256 + d0]);
    float4 y = make_float4(a.x + xv.x, a.y + xv.y, a.z + xv.z, a.w + xv.w);

    float s1 = y.x + y.y + y.z + y.w;
    float s2 = y.x * y.x + y.y * y.y + y.z * y.z + y.w * y.w;
    #pragma unroll
    for (int off = 32; off > 0; off >>= 1) {
        s1 += __shfl_xor(s1, off);
        s2 += __shfl_xor(s2, off);
    }
    const float mu = s1 * (1.0f / 256.0f);
    const float var = s2 * (1.0f / 256.0f) - mu * mu;
    const float istd = 1.0f / sqrtf(var + 0.001f);

    float4 g4 = *reinterpret_cast<const float4*>(&gamma[d0]);
    float4 b4 = *reinterpret_cast<const float4*>(&beta[d0]);
    float4 o;
    o.x = (y.x - mu) * istd * g4.x + b4.x;
    o.y = (y.y - mu) * istd * g4.y + b4.y;
    o.z = (y.z - mu) * istd * g4.z + b4.z;
    o.w = (y.w - mu) * istd * g4.w + b4.w;
    *reinterpret_cast<float4*>(&out[row * 256 + d0]) = o;
}

extern "C" void kernel_launch(void* const* d_in, const int* in_sizes, int n_in,
                              void* d_out, int out_size, void* d_ws, size_t ws_size,
                              hipStream_t stream)
{
    const float* x  = (const float*)d_in[0];
    const float* Wh = (const float*)d_in[1];
    const float* bh = (const float*)d_in[2];
    const float* Wd = (const float*)d_in[3];
    const float* bd = (const float*)d_in[4];
    const float* Wv = (const float*)d_in[5];
    const float* bv = (const float*)d_in[6];
    const float* g  = (const float*)d_in[7];
    const float* be = (const float*)d_in[8];
    float* out = (float*)d_out;

    char* ws = (char*)d_ws;
    float*          z     = (float*)ws;                       // 33554432 B
    float*          v     = (float*)(ws + 33554432);          // 33554432 B
    float*          simv  = (float*)(ws + 67108864);          // 131072 B
    int*            order = (int*)(ws + 67239936);            // 131072 B
    unsigned short* WdT   = (unsigned short*)(ws + 67371008); // 1048576 B
    unsigned short* WhH   = (unsigned short*)(ws + 68419584); // 1048576 B
    float*          WhT   = (float*)(ws + 69468160);          // 2097152 B
    unsigned short* WvT   = (unsigned short*)(ws + 71565312); // 131072 B
    unsigned short* q     = (unsigned short*)(ws + 71696384); // 134217728 B
    int*            gcnt  = (int*)(ws + 205914112);           // 32768 B
    int*            gls   = (int*)(ws + 205946880);           // 10485760 B -> end 216432640

    const bool big = ws_size >= 216432640ULL;
    const int rows = Bc * Nc;                                 // 32768

    k0_wdt<<<dim3(128), dim3(256), 0, stream>>>(Wd, WdT);
    k0_wht<<<dim3(128), dim3(256), 0, stream>>>(Wh, WhH, WhT);
    k0_wvt<<<dim3(16), dim3(256), 0, stream>>>(Wv, WvT);
    if (big) {
        hipMemsetAsync(gcnt, 0, 32768, stream);
        k1a_head<<<dim3(1024, 8), dim3(256), 0, stream>>>(x, bh, WhH, q, gcnt, gls);
        k1b_down<<<dim3(1024), dim3(256), 0, stream>>>(q, WdT, bd, z);
        k1r_lsh_simv<<<dim3(1024), dim3(256), 0, stream>>>(q, x, WhT, bh, gcnt, gls, simv);
    } else {
        k1_fused<<<dim3(rows / 32), dim3(256), 0, stream>>>(x, bh, WhT, WhH, WdT, bd, z, simv);
    }
    k2_rank<<<dim3(Bc * 16), dim3(256), 0, stream>>>(simv, order);
    k3_value<<<dim3(rows / 32), dim3(256), 0, stream>>>(z, order, WvT, bv, v);
    k4_attn_ln<<<dim3(rows / 4), dim3(256), 0, stream>>>(z, v, order, x, g, be, out);
}

// Round 20
// 771.629 us; speedup vs baseline: 1.1033x; 1.0600x over previous
//
#include <hip/hip_runtime.h>

constexpr int Bc = 8, Nc = 4096;

using short8 = __attribute__((ext_vector_type(8))) short;
using f32x4  = __attribute__((ext_vector_type(4))) float;

static __device__ __forceinline__ unsigned short f2bf(float f) {
    unsigned u = __float_as_uint(f);
    u += 0x7fffu + ((u >> 16) & 1u);     // RNE
    return (unsigned short)(u >> 16);
}
// XOR-swizzled byte offset for a [32][256] ushort LDS plane (16B-access safe)
static __device__ __forceinline__ int swz(int r, int k) {
    return (r << 9) + ((k << 1) ^ ((r & 7) << 4));
}

#define GBIN_CAP 320
#define GUARD    0.012f

// ---------------- K0a: Wd [h][d][e] f32 -> WdT [h][e][d] bf16 ----------------
__global__ __launch_bounds__(256)
void k0_wdt(const float* __restrict__ Wd, unsigned short* __restrict__ WdT)
{
    __shared__ float tile[64][65];
    const int h  = blockIdx.x >> 4;
    const int t  = blockIdx.x & 15;
    const int kb = (t >> 2) * 64, eb = (t & 3) * 64;
    const int tid = threadIdx.x;
    {
        const int krow = tid >> 2, ec = (tid & 3) * 16;
        const float* src = Wd + h * 65536 + (kb + krow) * 256 + eb + ec;
        #pragma unroll
        for (int i = 0; i < 4; ++i) {
            float4 v = *reinterpret_cast<const float4*>(src + i * 4);
            tile[krow][ec + i * 4 + 0] = v.x;
            tile[krow][ec + i * 4 + 1] = v.y;
            tile[krow][ec + i * 4 + 2] = v.z;
            tile[krow][ec + i * 4 + 3] = v.w;
        }
    }
    __syncthreads();
    {
        const int erow = tid >> 2, dc = (tid & 3) * 16;
        unsigned short o[16];
        #pragma unroll
        for (int i = 0; i < 16; ++i) o[i] = f2bf(tile[dc + i][erow]);
        unsigned short* dst = WdT + h * 65536 + (eb + erow) * 256 + kb + dc;
        *reinterpret_cast<short8*>(dst)     = *reinterpret_cast<short8*>(&o[0]);
        *reinterpret_cast<short8*>(dst + 8) = *reinterpret_cast<short8*>(&o[8]);
    }
}

// ---------------- K0b: Wh [k][h][e] f32 -> WhH bf16 [h][e][k] + WhT f32 [h][e][k] ----------------
__global__ __launch_bounds__(256)
void k0_wht(const float* __restrict__ Wh, unsigned short* __restrict__ WhH,
            float* __restrict__ WhT)
{
    __shared__ float tile[64][65];
    const int h  = blockIdx.x >> 4;
    const int t  = blockIdx.x & 15;
    const int kb = (t >> 2) * 64, eb = (t & 3) * 64;
    const int tid = threadIdx.x;
    {
        const int krow = tid >> 2, ec = (tid & 3) * 16;
        const float* src = Wh + (kb + krow) * 2048 + h * 256 + eb + ec;
        #pragma unroll
        for (int i = 0; i < 4; ++i) {
            float4 v = *reinterpret_cast<const float4*>(src + i * 4);
            tile[krow][ec + i * 4 + 0] = v.x;
            tile[krow][ec + i * 4 + 1] = v.y;
            tile[krow][ec + i * 4 + 2] = v.z;
            tile[krow][ec + i * 4 + 3] = v.w;
        }
    }
    __syncthreads();
    {
        const int erow = tid >> 2, dc = (tid & 3) * 16;
        unsigned short o[16];
        float of[16];
        #pragma unroll
        for (int i = 0; i < 16; ++i) {
            of[i] = tile[dc + i][erow];
            o[i] = f2bf(of[i]);
        }
        const long base = (long)h * 65536 + (eb + erow) * 256 + kb + dc;
        *reinterpret_cast<short8*>(WhH + base)     = *reinterpret_cast<short8*>(&o[0]);
        *reinterpret_cast<short8*>(WhH + base + 8) = *reinterpret_cast<short8*>(&o[8]);
        #pragma unroll
        for (int i = 0; i < 16; i += 4)
            *reinterpret_cast<float4*>(WhT + base + i) = *reinterpret_cast<const float4*>(&of[i]);
    }
}

// ---------------- K0c: Wv [k][e] f32 -> WvT [e][k] bf16 ----------------
__global__ __launch_bounds__(256)
void k0_wvt(const float* __restrict__ Wv, unsigned short* __restrict__ WvT)
{
    __shared__ float tile[64][65];
    const int t  = blockIdx.x;
    const int kb = (t >> 2) * 64, eb = (t & 3) * 64;
    const int tid = threadIdx.x;
    {
        const int krow = tid >> 2, ec = (tid & 3) * 16;
        const float* src = Wv + (kb + krow) * 256 + eb + ec;
        #pragma unroll
        for (int i = 0; i < 4; ++i) {
            float4 v = *reinterpret_cast<const float4*>(src + i * 4);
            tile[krow][ec + i * 4 + 0] = v.x;
            tile[krow][ec + i * 4 + 1] = v.y;
            tile[krow][ec + i * 4 + 2] = v.z;
            tile[krow][ec + i * 4 + 3] = v.w;
        }
    }
    __syncthreads();
    {
        const int erow = tid >> 2, dc = (tid & 3) * 16;
        unsigned short o[16];
        #pragma unroll
        for (int i = 0; i < 16; ++i) o[i] = f2bf(tile[dc + i][erow]);
        unsigned short* dst = WvT + (eb + erow) * 256 + kb + dc;
        *reinterpret_cast<short8*>(dst)     = *reinterpret_cast<short8*>(&o[0]);
        *reinterpret_cast<short8*>(dst + 8) = *reinterpret_cast<short8*>(&o[8]);
    }
}

// ================= SPLIT PATH =================
// ---------------- K1a: head GEMM (one h per block), q bf16 + guard bins ----------------
__global__ __launch_bounds__(256, 3)
void k1a_head(const float* __restrict__ x, const float* __restrict__ bh,
              const unsigned short* __restrict__ WhH,
              unsigned short* __restrict__ q, int* __restrict__ gcnt, int* __restrict__ gls)
{
    __shared__ __align__(16) char SM[16384];   // x tile, then reused as q tile

    const int tid = threadIdx.x;
    const long rowbase = (long)blockIdx.x * 32;
    const int h = blockIdx.y;
    const int wavei = tid >> 6, lane = tid & 63;
    const int mrow = lane & 15, kgrp = lane >> 4;
    const int ebase = wavei * 64 + mrow;
    const int kfo = kgrp * 8;
    const unsigned short* whh = WhH + ((long)h << 16);

    short8 hB[4][4];
    #pragma unroll
    for (int i = 0; i < 4; ++i)
        #pragma unroll
        for (int nf = 0; nf < 4; ++nf)
            hB[i][nf] = *reinterpret_cast<const short8*>(
                &whh[(ebase + nf * 16) * 256 + i * 32 + kfo]);

    {   // x -> bf16 LDS (swizzled)
        const int r = tid >> 3, kc = (tid & 7) * 32;
        const float* src = x + (rowbase + r) * 256 + kc;
        unsigned short oh[32];
        #pragma unroll
        for (int i = 0; i < 32; i += 4) {
            float4 v = *reinterpret_cast<const float4*>(src + i);
            oh[i + 0] = f2bf(v.x); oh[i + 1] = f2bf(v.y);
            oh[i + 2] = f2bf(v.z); oh[i + 3] = f2bf(v.w);
        }
        #pragma unroll
        for (int i = 0; i < 32; i += 8)
            *reinterpret_cast<short8*>(SM + swz(r, kc + i)) =
                *reinterpret_cast<short8*>(&oh[i]);
    }
    __syncthreads();

    f32x4 hacc[2][4];
    #pragma unroll
    for (int mt = 0; mt < 2; ++mt)
        #pragma unroll
        for (int nf = 0; nf < 4; ++nf) hacc[mt][nf] = (f32x4){0.f, 0.f, 0.f, 0.f};
    #pragma unroll
    for (int kt = 0; kt < 8; ++kt) {
        const int k0 = kt * 32 + kfo;
        short8 a0 = *reinterpret_cast<const short8*>(SM + swz(mrow, k0));
        short8 a1 = *reinterpret_cast<const short8*>(SM + swz(16 + mrow, k0));
        #pragma unroll
        for (int nf = 0; nf < 4; ++nf) {
            hacc[0][nf] = __builtin_amdgcn_mfma_f32_16x16x32_bf16(a0, hB[kt & 3][nf], hacc[0][nf], 0, 0, 0);
            hacc[1][nf] = __builtin_amdgcn_mfma_f32_16x16x32_bf16(a1, hB[kt & 3][nf], hacc[1][nf], 0, 0, 0);
        }
        if (kt < 4) {
            #pragma unroll
            for (int nf = 0; nf < 4; ++nf)
                hB[kt][nf] = *reinterpret_cast<const short8*>(
                    &whh[(ebase + nf * 16) * 256 + (kt + 4) * 32 + kfo]);
        }
    }
    float bias[4];
    #pragma unroll
    for (int nf = 0; nf < 4; ++nf) bias[nf] = bh[(h << 8) + ebase + nf * 16];
    __syncthreads();   // all waves done reading x tile -> reuse as q tile
    const int bin = (int)blockIdx.x * 8 + h;
    #pragma unroll
    for (int mt = 0; mt < 2; ++mt) {
        #pragma unroll
        for (int nf = 0; nf < 4; ++nf) {
            const int e = ebase + nf * 16;
            #pragma unroll
            for (int reg = 0; reg < 4; ++reg) {
                const int r = mt * 16 + kgrp * 4 + reg;
                const float pre = __fadd_rn(hacc[mt][nf][reg], bias[nf]);
                if (fabsf(pre) < GUARD) {
                    int idx = atomicAdd(&gcnt[bin], 1);
                    if (idx < GBIN_CAP)
                        gls[bin * GBIN_CAP + idx] =
                            r | (e << 5) | ((pre > 0.0f ? 1 : 0) << 13);
                }
                *reinterpret_cast<unsigned short*>(SM + swz(r, e)) =
                    f2bf(fmaxf(pre, 0.0f));
            }
        }
    }
    __syncthreads();
    {   // coalesced q store
        const int r = tid >> 3, ec = (tid & 7) * 32;
        unsigned short* dst = q + (rowbase + r) * 2048 + (h << 8) + ec;
        #pragma unroll
        for (int i = 0; i < 4; ++i)
            *reinterpret_cast<short8*>(dst + i * 8) =
                *reinterpret_cast<short8*>(SM + swz(r, ec + i * 8));
    }
}

// K1b LDS map
#define B_VALQ 0       // valq[32][256] f32 32KB (A-tile uses [0,16K) during GEMM)
#define B_LSH8 32768   // s8[256e][32r] 8KB
#define B_PE   40960
#define B_CF   41984
#define B_CNT  43008   // int[32][16]
#define B_CCN  45056
#define B_CLS  45060   // int[128]
#define B_CLS_CAP 128

// ---------------- K1b: down GEMM + fused lsh/guard/simv ----------------
__global__ __launch_bounds__(256, 3)
void k1b_down(const unsigned short* __restrict__ q,
              const unsigned short* __restrict__ WdT, const float* __restrict__ bd,
              const float* __restrict__ x, const float* __restrict__ WhT,
              const float* __restrict__ bh,
              const int* __restrict__ gcnt, const int* __restrict__ gls,
              float* __restrict__ z, float* __restrict__ simv)
{
    __shared__ __align__(16) char SM[45576];

    const int tid = threadIdx.x;
    const long rowbase = (long)blockIdx.x * 32;
    const int wavei = tid >> 6, lane = tid & 63;
    const int mrow = lane & 15, kgrp = lane >> 4;
    const int ebase = wavei * 64 + mrow;
    const int kfo = kgrp * 8;

    short8 dB[4][4];
    #pragma unroll
    for (int i = 0; i < 4; ++i)
        #pragma unroll
        for (int nf = 0; nf < 4; ++nf)
            dB[i][nf] = *reinterpret_cast<const short8*>(
                &WdT[(ebase + nf * 16) * 256 + i * 32 + kfo]);

    {   // XLA:CPU twin tables (CR libm via f64-round) — overlaps dB flight
        const int d = tid;
        const float u = -((float)d * 0.00390625f);
        const float freq = (float)pow(10.0, (double)u);
        const float pe = (d & 1) ? (float)sin((double)freq)
                                 : (float)cos((double)freq);
        ((float*)(SM + B_PE))[d] = __fdiv_rn(pe, 0.4f);
        ((float*)(SM + B_CF))[d] = __fmul_rn(0.4f, (float)pow((double)0.6f, (double)d));
    }
    if (tid == 0) *(int*)(SM + B_CCN) = 0;

    f32x4 dacc[2][4];
    #pragma unroll
    for (int mt = 0; mt < 2; ++mt)
        #pragma unroll
        for (int nf = 0; nf < 4; ++nf) dacc[mt][nf] = (f32x4){0.f, 0.f, 0.f, 0.f};
    unsigned lshp[4] = {0u, 0u, 0u, 0u};   // 32 nibble counters: (r=tid>>3, e=(tid&7)*32+jj)
    __syncthreads();   // tables ready, and SM[0,16K) free

    for (int kc = 0; kc < 8; ++kc) {
        const unsigned short* wdh = WdT + ((long)kc << 16);
        {   // stage A chunk: rows 32 x k 256 (k within chunk; chunk kc == h)
            const int r = tid >> 3, kb2 = (tid & 7) * 32;
            const unsigned short* src = q + (rowbase + r) * 2048 + (kc << 8) + kb2;
            short8 t0 = *reinterpret_cast<const short8*>(src);
            short8 t1 = *reinterpret_cast<const short8*>(src + 8);
            short8 t2 = *reinterpret_cast<const short8*>(src + 16);
            short8 t3 = *reinterpret_cast<const short8*>(src + 24);
            *reinterpret_cast<short8*>(SM + swz(r, kb2))      = t0;
            *reinterpret_cast<short8*>(SM + swz(r, kb2 + 8))  = t1;
            *reinterpret_cast<short8*>(SM + swz(r, kb2 + 16)) = t2;
            *reinterpret_cast<short8*>(SM + swz(r, kb2 + 24)) = t3;
            // lsh sign scan directly from the staged registers (q bf16 != 0 <=> pre > 0)
            #pragma unroll
            for (int j = 0; j < 8; ++j) {
                lshp[0] += (((unsigned short)t0[j] != 0) ? 1u : 0u) << (4 * (j & 7));
                lshp[1] += (((unsigned short)t1[j] != 0) ? 1u : 0u) << (4 * (j & 7));
                lshp[2] += (((unsigned short)t2[j] != 0) ? 1u : 0u) << (4 * (j & 7));
                lshp[3] += (((unsigned short)t3[j] != 0) ? 1u : 0u) << (4 * (j & 7));
            }
        }
        __syncthreads();
        #pragma unroll
        for (int ks = 0; ks < 8; ++ks) {
            const int k0 = ks * 32 + kfo;
            short8 a0 = *reinterpret_cast<const short8*>(SM + swz(mrow, k0));
            short8 a1 = *reinterpret_cast<const short8*>(SM + swz(16 + mrow, k0));
            #pragma unroll
            for (int nf = 0; nf < 4; ++nf) {
                dacc[0][nf] = __builtin_amdgcn_mfma_f32_16x16x32_bf16(a0, dB[ks & 3][nf], dacc[0][nf], 0, 0, 0);
                dacc[1][nf] = __builtin_amdgcn_mfma_f32_16x16x32_bf16(a1, dB[ks & 3][nf], dacc[1][nf], 0, 0, 0);
            }
            if (ks < 4) {
                #pragma unroll
                for (int nf = 0; nf < 4; ++nf)
                    dB[ks][nf] = *reinterpret_cast<const short8*>(
                        &wdh[(ebase + nf * 16) * 256 + (ks + 4) * 32 + kfo]);
            } else if (kc < 7) {
                #pragma unroll
                for (int nf = 0; nf < 4; ++nf)
                    dB[ks - 4][nf] = *reinterpret_cast<const short8*>(
                        &WdT[((long)(kc + 1) << 16) + (ebase + nf * 16) * 256 + (ks - 4) * 32 + kfo]);
            }
        }
        __syncthreads();
    }
    // ---- epilogue: z = relu(dacc + bd) ----
    #pragma unroll
    for (int mt = 0; mt < 2; ++mt) {
        #pragma unroll
        for (int nf = 0; nf < 4; ++nf) {
            const int e = ebase + nf * 16;
            const float b = bd[e];
            #pragma unroll
            for (int reg = 0; reg < 4; ++reg)
                z[(rowbase + mt * 16 + kgrp * 4 + reg) * 256 + e] =
                    fmaxf(dacc[mt][nf][reg] + b, 0.0f);
        }
    }
    // ---- lsh decode -> int8 plane; counters: jj-th nibble of lshp[i] is e=(tid&7)*32+i*8+jj ----
    {
        signed char* lsh8 = (signed char*)(SM + B_LSH8);
        const int r = tid >> 3, e0 = (tid & 7) * 32;
        #pragma unroll
        for (int i = 0; i < 4; ++i)
            #pragma unroll
            for (int j = 0; j < 8; ++j) {
                const unsigned p = (lshp[i] >> (4 * j)) & 15u;
                lsh8[(e0 + i * 8 + j) * 32 + r] = (signed char)(2 * (int)p - 8);
            }
    }
    __syncthreads();
    // ---- guard fixes: exact ascending-k f32 chain (r9-verified semantics) ----
    for (int h = 0; h < 8; ++h) {
        const int bin = (int)blockIdx.x * 8 + h;
        int n = gcnt[bin];
        n = n < GBIN_CAP ? n : GBIN_CAP;
        for (int i = tid; i < n; i += 256) {
            const int ent = gls[bin * GBIN_CAP + i];
            const int r = ent & 31, e = (ent >> 5) & 255;
            const int fs = ((ent >> 13) & 1) ? 1 : -1;
            const float* xr = x + (rowbase + r) * 256;
            const float* wrow = WhT + (((long)h << 8) + e) * 256;
            float acc = 0.0f;
            for (int k = 0; k < 256; k += 4) {
                float4 xv = *reinterpret_cast<const float4*>(xr + k);
                float4 wv = *reinterpret_cast<const float4*>(wrow + k);
                acc = fmaf(xv.x, wv.x, acc);
                acc = fmaf(xv.y, wv.y, acc);
                acc = fmaf(xv.z, wv.z, acc);
                acc = fmaf(xv.w, wv.w, acc);
            }
            const float pre = __fadd_rn(acc, bh[h * 256 + e]);
            const int es = (pre > 0.0f) ? 1 : -1;
            if (es != fs) {
                int ci = atomicAdd((int*)(SM + B_CCN), 1);
                if (ci < B_CLS_CAP)
                    ((int*)(SM + B_CLS))[ci] = r | (e << 5) | ((es > 0 ? 1 : 0) << 13);
            }
        }
    }
    __syncthreads();
    if (tid == 0) {   // apply corrections serially (race-free byte RMW)
        signed char* lsh8 = (signed char*)(SM + B_LSH8);
        int cn = *(int*)(SM + B_CCN);
        cn = cn < B_CLS_CAP ? cn : B_CLS_CAP;
        for (int i = 0; i < cn; ++i) {
            const int ent = ((int*)(SM + B_CLS))[i];
            const int r = ent & 31, e = (ent >> 5) & 255;
            const int d = ((ent >> 13) & 1) ? 2 : -2;
            lsh8[e * 32 + r] = (signed char)(lsh8[e * 32 + r] + d);
        }
    }
    __syncthreads();
    // ---- tail: stable counting sort + simv (bit-exact, r9-verified) ----
    if (tid < 32) {
        const int r = tid;
        const signed char* lsh8 = (const signed char*)(SM + B_LSH8);
        const float* pe_over = (const float*)(SM + B_PE);
        const float* c_f = (const float*)(SM + B_CF);
        int* cw = (int*)(SM + B_CNT) + r * 16;
        for (int i = 0; i < 9; ++i) cw[i] = 0;
        for (int d = 0; d < 256; ++d) {
            int vv = (int)lsh8[d * 32 + r];
            cw[(vv + 8) >> 1] += 1;
        }
        int run = 0;
        for (int bin = 8; bin >= 0; --bin) { int c0 = cw[bin]; cw[bin] = run; run += c0; }
        float* valq = (float*)(SM + B_VALQ + r * 1024);
        for (int d = 0; d < 256; ++d) {
            int vv = (int)lsh8[d * 32 + r];
            int bin = (vv + 8) >> 1;
            int j = cw[bin]++;
            valq[j] = __fadd_rn((float)vv, pe_over[d]);
        }
        float L0 = 0.f, L1 = 0.f, L2 = 0.f, L3 = 0.f,
              L4 = 0.f, L5 = 0.f, L6 = 0.f, L7 = 0.f;
        for (int i = 0; i < 256; i += 8) {
            L0 = fmaf(valq[i + 0], c_f[i + 0], L0);
            L1 = fmaf(valq[i + 1], c_f[i + 1], L1);
            L2 = fmaf(valq[i + 2], c_f[i + 2], L2);
            L3 = fmaf(valq[i + 3], c_f[i + 3], L3);
            L4 = fmaf(valq[i + 4], c_f[i + 4], L4);
            L5 = fmaf(valq[i + 5], c_f[i + 5], L5);
            L6 = fmaf(valq[i + 6], c_f[i + 6], L6);
            L7 = fmaf(valq[i + 7], c_f[i + 7], L7);
        }
        const float h0 = __fadd_rn(L0, L4);
        const float h1 = __fadd_rn(L1, L5);
        const float h2 = __fadd_rn(L2, L6);
        const float h3 = __fadd_rn(L3, L7);
        simv[rowbase + r] = __fadd_rn(__fadd_rn(h0, h2), __fadd_rn(h1, h3));
    }
}

// ================= FALLBACK (r14 fused kernel, best proven) =================
#define XSH_OFF  0
#define QTB_OFF  16384
#define LSH8_OFF 32768
#define PE_OFF   40960
#define CF_OFF   41984
#define CNT_OFF  43008
#define FCN_OFF  45056
#define CCN_OFF  45060
#define FLS_OFF  45064
#define CLS_OFF  49160
#define FLS_CAP  1024
#define CLS_CAP  96

__global__ __launch_bounds__(256, 3)
void k1_fused(const float* __restrict__ x,
              const float* __restrict__ bh,
              const float* __restrict__ WhT,
              const unsigned short* __restrict__ WhH,
              const unsigned short* __restrict__ WdT, const float* __restrict__ bd,
              float* __restrict__ z, float* __restrict__ simv)
{
    __shared__ __align__(16) char SM[49600];
    const int tid = threadIdx.x;
    const long rowbase = (long)blockIdx.x * 32;
    const int wavei = tid >> 6, lane = tid & 63;
    const int mrow = lane & 15, kgrp = lane >> 4;
    const int ebase = wavei * 64 + mrow;
    const int kfo = kgrp * 8;

    short8 hB[3][4], dB[3][4];
    #pragma unroll
    for (int i = 0; i < 2; ++i)
        #pragma unroll
        for (int nf = 0; nf < 4; ++nf)
            hB[i][nf] = *reinterpret_cast<const short8*>(
                &WhH[(ebase + nf * 16) * 256 + i * 32 + kfo]);
    {
        const int d = tid;
        const float u = -((float)d * 0.00390625f);
        const float freq = (float)pow(10.0, (double)u);
        const float pe = (d & 1) ? (float)sin((double)freq)
                                 : (float)cos((double)freq);
        ((float*)(SM + PE_OFF))[d] = __fdiv_rn(pe, 0.4f);
        ((float*)(SM + CF_OFF))[d] = __fmul_rn(0.4f, (float)pow((double)0.6f, (double)d));
    }
    if (tid == 0) { *(int*)(SM + FCN_OFF) = 0; *(int*)(SM + CCN_OFF) = 0; }
    {
        const int r = tid >> 3, kc = (tid & 7) * 32;
        const float* src = x + (rowbase + r) * 256 + kc;
        unsigned short oh[32];
        #pragma unroll
        for (int i = 0; i < 32; i += 4) {
            float4 v = *reinterpret_cast<const float4*>(src + i);
            oh[i + 0] = f2bf(v.x); oh[i + 1] = f2bf(v.y);
            oh[i + 2] = f2bf(v.z); oh[i + 3] = f2bf(v.w);
        }
        #pragma unroll
        for (int i = 0; i < 32; i += 8)
            *reinterpret_cast<short8*>(SM + XSH_OFF + swz(r, kc + i)) =
                *reinterpret_cast<short8*>(&oh[i]);
    }
    unsigned lshp[4] = {0u, 0u, 0u, 0u};
    f32x4 dacc[2][4];
    #pragma unroll
    for (int mt = 0; mt < 2; ++mt)
        #pragma unroll
        for (int nf = 0; nf < 4; ++nf) dacc[mt][nf] = (f32x4){0.f, 0.f, 0.f, 0.f};
    __syncthreads();
    for (int h = 0; h < 8; ++h) {
        const unsigned short* whh = WhH + ((long)h << 16);
        const unsigned short* wdh = WdT + ((long)h << 16);
        float bias[4];
        #pragma unroll
        for (int nf = 0; nf < 4; ++nf) bias[nf] = bh[(h << 8) + ebase + nf * 16];
        f32x4 hacc[2][4];
        #pragma unroll
        for (int mt = 0; mt < 2; ++mt)
            #pragma unroll
            for (int nf = 0; nf < 4; ++nf) hacc[mt][nf] = (f32x4){0.f, 0.f, 0.f, 0.f};
        #pragma unroll
        for (int kt = 0; kt < 8; ++kt) {
            const int k0 = kt * 32 + kfo;
            short8 a0 = *reinterpret_cast<const short8*>(SM + XSH_OFF + swz(mrow, k0));
            short8 a1 = *reinterpret_cast<const short8*>(SM + XSH_OFF + swz(16 + mrow, k0));
            if (kt < 6) {
                #pragma unroll
                for (int nf = 0; nf < 4; ++nf)
                    hB[(kt + 2) % 3][nf] = *reinterpret_cast<const short8*>(
                        &whh[(ebase + nf * 16) * 256 + (kt + 2) * 32 + kfo]);
            }
            #pragma unroll
            for (int nf = 0; nf < 4; ++nf) {
                hacc[0][nf] = __builtin_amdgcn_mfma_f32_16x16x32_bf16(a0, hB[kt % 3][nf], hacc[0][nf], 0, 0, 0);
                hacc[1][nf] = __builtin_amdgcn_mfma_f32_16x16x32_bf16(a1, hB[kt % 3][nf], hacc[1][nf], 0, 0, 0);
            }
        }
        #pragma unroll
        for (int i = 0; i < 2; ++i)
            #pragma unroll
            for (int nf = 0; nf < 4; ++nf)
                dB[i][nf] = *reinterpret_cast<const short8*>(
                    &wdh[(ebase + nf * 16) * 256 + i * 32 + kfo]);
        #pragma unroll
        for (int mt = 0; mt < 2; ++mt) {
            #pragma unroll
            for (int nf = 0; nf < 4; ++nf) {
                const int e = ebase + nf * 16;
                #pragma unroll
                for (int reg = 0; reg < 4; ++reg) {
                    const int r = mt * 16 + kgrp * 4 + reg;
                    const float pre = __fadd_rn(hacc[mt][nf][reg], bias[nf]);
                    const unsigned pos = (pre > 0.0f) ? 1u : 0u;
                    const int j = mt * 16 + nf * 4 + reg;
                    lshp[j >> 3] += pos << (4 * (j & 7));
                    if (fabsf(pre) < GUARD) {
                        int idx = atomicAdd((int*)(SM + FCN_OFF), 1);
                        if (idx < FLS_CAP)
                            ((int*)(SM + FLS_OFF))[idx] =
                                r | (e << 5) | (h << 13) | ((int)pos << 16);
                    }
                    *reinterpret_cast<unsigned short*>(SM + QTB_OFF + swz(r, e)) =
                        f2bf(fmaxf(pre, 0.0f));
                }
            }
        }
        __syncthreads();
        #pragma unroll
        for (int ks = 0; ks < 8; ++ks) {
            const int k0 = ks * 32 + kfo;
            short8 a0 = *reinterpret_cast<const short8*>(SM + QTB_OFF + swz(mrow, k0));
            short8 a1 = *reinterpret_cast<const short8*>(SM + QTB_OFF + swz(16 + mrow, k0));
            if (ks < 6) {
                #pragma unroll
                for (int nf = 0; nf < 4; ++nf)
                    dB[(ks + 2) % 3][nf] = *reinterpret_cast<const short8*>(
                        &wdh[(ebase + nf * 16) * 256 + (ks + 2) * 32 + kfo]);
            } else if (h < 7) {
                const int i = ks - 6;
                #pragma unroll
                for (int nf = 0; nf < 4; ++nf)
                    hB[i][nf] = *reinterpret_cast<const short8*>(
                        &WhH[((long)(h + 1) << 16) + (ebase + nf * 16) * 256 + i * 32 + kfo]);
            }
            #pragma unroll
            for (int nf = 0; nf < 4; ++nf) {
                dacc[0][nf] = __builtin_amdgcn_mfma_f32_16x16x32_bf16(a0, dB[ks % 3][nf], dacc[0][nf], 0, 0, 0);
                dacc[1][nf] = __builtin_amdgcn_mfma_f32_16x16x32_bf16(a1, dB[ks % 3][nf], dacc[1][nf], 0, 0, 0);
            }
        }
        __syncthreads();
    }
    #pragma unroll
    for (int mt = 0; mt < 2; ++mt) {
        #pragma unroll
        for (int nf = 0; nf < 4; ++nf) {
            const int e = ebase + nf * 16;
            const float b = bd[e];
            #pragma unroll
            for (int reg = 0; reg < 4; ++reg)
                z[(rowbase + mt * 16 + kgrp * 4 + reg) * 256 + e] =
                    fmaxf(dacc[mt][nf][reg] + b, 0.0f);
        }
    }
    {
        signed char* lsh8 = (signed char*)(SM + LSH8_OFF);
        #pragma unroll
        for (int mt = 0; mt < 2; ++mt)
            #pragma unroll
            for (int nf = 0; nf < 4; ++nf) {
                const int e = ebase + nf * 16;
                #pragma unroll
                for (int reg = 0; reg < 4; ++reg) {
                    const int r = mt * 16 + kgrp * 4 + reg;
                    const int j = mt * 16 + nf * 4 + reg;
                    const unsigned p = (lshp[j >> 3] >> (4 * (j & 7))) & 15u;
                    lsh8[e * 32 + r] = (signed char)(2 * (int)p - 8);
                }
            }
    }
    __syncthreads();
    {
        int n = *((int*)(SM + FCN_OFF));
        n = n < FLS_CAP ? n : FLS_CAP;
        for (int i = tid; i < n; i += 256) {
            const int ent = ((int*)(SM + FLS_OFF))[i];
            const int r = ent & 31, e = (ent >> 5) & 255, hh2 = (ent >> 13) & 7;
            const int fs = ((ent >> 16) & 1) ? 1 : -1;
            const float* xr = x + (rowbase + r) * 256;
            const float* wrow = WhT + (((long)hh2 << 8) + e) * 256;
            float acc = 0.0f;
            for (int k = 0; k < 256; k += 4) {
                float4 xv = *reinterpret_cast<const float4*>(xr + k);
                float4 wv = *reinterpret_cast<const float4*>(wrow + k);
                acc = fmaf(xv.x, wv.x, acc);
                acc = fmaf(xv.y, wv.y, acc);
                acc = fmaf(xv.z, wv.z, acc);
                acc = fmaf(xv.w, wv.w, acc);
            }
            const float pre = __fadd_rn(acc, bh[hh2 * 256 + e]);
            const int es = (pre > 0.0f) ? 1 : -1;
            if (es != fs) {
                int ci = atomicAdd((int*)(SM + CCN_OFF), 1);
                if (ci < CLS_CAP)
                    ((int*)(SM + CLS_OFF))[ci] = r | (e << 5) | ((es > 0 ? 1 : 0) << 13);
            }
        }
    }
    __syncthreads();
    if (tid == 0) {
        signed char* lsh8 = (signed char*)(SM + LSH8_OFF);
        int cn = *((int*)(SM + CCN_OFF));
        cn = cn < CLS_CAP ? cn : CLS_CAP;
        for (int i = 0; i < cn; ++i) {
            const int ent = ((int*)(SM + CLS_OFF))[i];
            const int r = ent & 31, e = (ent >> 5) & 255;
            const int d = ((ent >> 13) & 1) ? 2 : -2;
            lsh8[e * 32 + r] = (signed char)(lsh8[e * 32 + r] + d);
        }
    }
    __syncthreads();
    if (tid < 32) {
        const int r = tid;
        const signed char* lsh8 = (const signed char*)(SM + LSH8_OFF);
        const float* pe_over = (const float*)(SM + PE_OFF);
        const float* c_f = (const float*)(SM + CF_OFF);
        int* cw = (int*)(SM + CNT_OFF) + r * 16;
        for (int i = 0; i < 9; ++i) cw[i] = 0;
        for (int d = 0; d < 256; ++d) {
            int vv = (int)lsh8[d * 32 + r];
            cw[(vv + 8) >> 1] += 1;
        }
        int run = 0;
        for (int bin = 8; bin >= 0; --bin) { int c0 = cw[bin]; cw[bin] = run; run += c0; }
        float* valq = (float*)(SM + r * 1024);
        for (int d = 0; d < 256; ++d) {
            int vv = (int)lsh8[d * 32 + r];
            int bin = (vv + 8) >> 1;
            int j = cw[bin]++;
            valq[j] = __fadd_rn((float)vv, pe_over[d]);
        }
        float L0 = 0.f, L1 = 0.f, L2 = 0.f, L3 = 0.f,
              L4 = 0.f, L5 = 0.f, L6 = 0.f, L7 = 0.f;
        for (int i = 0; i < 256; i += 8) {
            L0 = fmaf(valq[i + 0], c_f[i + 0], L0);
            L1 = fmaf(valq[i + 1], c_f[i + 1], L1);
            L2 = fmaf(valq[i + 2], c_f[i + 2], L2);
            L3 = fmaf(valq[i + 3], c_f[i + 3], L3);
            L4 = fmaf(valq[i + 4], c_f[i + 4], L4);
            L5 = fmaf(valq[i + 5], c_f[i + 5], L5);
            L6 = fmaf(valq[i + 6], c_f[i + 6], L6);
            L7 = fmaf(valq[i + 7], c_f[i + 7], L7);
        }
        const float h0 = __fadd_rn(L0, L4);
        const float h1 = __fadd_rn(L1, L5);
        const float h2 = __fadd_rn(L2, L6);
        const float h3 = __fadd_rn(L3, L7);
        simv[rowbase + r] = __fadd_rn(__fadd_rn(h0, h2), __fadd_rn(h1, h3));
    }
}

// ---------------- K2: stable rank -> order ----------------
__global__ __launch_bounds__(256)
void k2_rank(const float* __restrict__ simv, int* __restrict__ order)
{
    __shared__ float s_l[4096];
    const int b = blockIdx.x >> 4;
    const int chunk = blockIdx.x & 15;
    const float* S = simv + (long)b * 4096;
    for (int i = threadIdx.x; i < 4096; i += 256) s_l[i] = S[i];
    __syncthreads();
    const int n = chunk * 256 + threadIdx.x;
    const float key = s_l[n];
    int cnt = 0;
    for (int m = 0; m < 4096; ++m) {
        float sm = s_l[m];
        cnt += (sm < key) ? 1 : ((sm == key && m < n) ? 1 : 0);
    }
    order[(long)b * 4096 + cnt] = n;
}

// ---------------- K3: value GEMM on gathered rows (bf16 MFMA) ----------------
__global__ __launch_bounds__(256, 3)
void k3_value(const float* __restrict__ z, const int* __restrict__ order,
              const unsigned short* __restrict__ WvT, const float* __restrict__ bv,
              float* __restrict__ v)
{
    __shared__ __align__(16) unsigned short ZB[32 * 256];
    __shared__ int ord[32];
    const int tid = threadIdx.x;
    const long rowbase = (long)blockIdx.x * 32;
    const long bbase = (rowbase >> 12) << 12;
    const int wavei = tid >> 6, lane = tid & 63;
    const int mrow = lane & 15, kgrp = lane >> 4;
    const int ebase = wavei * 64 + mrow;
    const int kfo = kgrp * 8;

    if (tid < 32) ord[tid] = order[rowbase + tid];

    short8 vB[3][4];
    #pragma unroll
    for (int i = 0; i < 2; ++i)
        #pragma unroll
        for (int nf = 0; nf < 4; ++nf)
            vB[i][nf] = *reinterpret_cast<const short8*>(
                &WvT[(ebase + nf * 16) * 256 + i * 32 + kfo]);

    __syncthreads();
    {
        const int r = tid >> 3, kc = (tid & 7) * 32;
        const float* src = z + (bbase + ord[r]) * 256 + kc;
        unsigned short oh[32];
        #pragma unroll
        for (int i = 0; i < 32; i += 4) {
            float4 vv = *reinterpret_cast<const float4*>(src + i);
            oh[i + 0] = f2bf(vv.x); oh[i + 1] = f2bf(vv.y);
            oh[i + 2] = f2bf(vv.z); oh[i + 3] = f2bf(vv.w);
        }
        #pragma unroll
        for (int i = 0; i < 32; i += 8)
            *reinterpret_cast<short8*>((char*)ZB + swz(r, kc + i)) =
                *reinterpret_cast<short8*>(&oh[i]);
    }
    __syncthreads();

    f32x4 acc[2][4];
    #pragma unroll
    for (int mt = 0; mt < 2; ++mt)
        #pragma unroll
        for (int nf = 0; nf < 4; ++nf) acc[mt][nf] = (f32x4){0.f, 0.f, 0.f, 0.f};
    #pragma unroll
    for (int kt = 0; kt < 8; ++kt) {
        const int k0 = kt * 32 + kfo;
        short8 a0 = *reinterpret_cast<const short8*>((char*)ZB + swz(mrow, k0));
        short8 a1 = *reinterpret_cast<const short8*>((char*)ZB + swz(16 + mrow, k0));
        if (kt < 6) {
            #pragma unroll
            for (int nf = 0; nf < 4; ++nf)
                vB[(kt + 2) % 3][nf] = *reinterpret_cast<const short8*>(
                    &WvT[(ebase + nf * 16) * 256 + (kt + 2) * 32 + kfo]);
        }
        #pragma unroll
        for (int nf = 0; nf < 4; ++nf) {
            acc[0][nf] = __builtin_amdgcn_mfma_f32_16x16x32_bf16(a0, vB[kt % 3][nf], acc[0][nf], 0, 0, 0);
            acc[1][nf] = __builtin_amdgcn_mfma_f32_16x16x32_bf16(a1, vB[kt % 3][nf], acc[1][nf], 0, 0, 0);
        }
    }
    #pragma unroll
    for (int mt = 0; mt < 2; ++mt) {
        #pragma unroll
        for (int nf = 0; nf < 4; ++nf) {
            const int e = ebase + nf * 16;
            const float b = bv[e];
            #pragma unroll
            for (int reg = 0; reg < 4; ++reg)
                v[(rowbase + mt * 16 + kgrp * 4 + reg) * 256 + e] =
                    fmaxf(acc[mt][nf][reg] + b, 0.0f);
        }
    }
}

// ---------------- K4: windowed attention + residual + LayerNorm ----------------
__global__ __launch_bounds__(256)
void k4_attn_ln(const float* __restrict__ z, const float* __restrict__ v,
                const int* __restrict__ order, const float* __restrict__ x,
                const float* __restrict__ gamma, const float* __restrict__ beta,
                float* __restrict__ out)
{
    const int tid = threadIdx.x;
    const int wv = tid >> 6, lane = tid & 63;
    const long row = (long)blockIdx.x * 4 + wv;
    const int n = (int)(row & 4095);
    const long bbase = row - n;
    int start = n - 4;
    start = start < 0 ? 0 : start;
    start = start > (Nc - 9) ? (Nc - 9) : start;
    const int d0 = lane * 4;

    const int srcq = order[bbase + n];
    float4 q4 = *reinterpret_cast<const float4*>(&z[(bbase + srcq) * 256 + d0]);

    float t[9];
    #pragma unroll
    for (int w = 0; w < 9; ++w) {
        int srcm = order[bbase + start + w];
        float4 kv = *reinterpret_cast<const float4*>(&z[(bbase + srcm) * 256 + d0]);
        float p = q4.x * kv.x + q4.y * kv.y + q4.z * kv.z + q4.w * kv.w;
        #pragma unroll
        for (int off = 32; off > 0; off >>= 1) p += __shfl_xor(p, off);
        t[w] = p * 0.0625f;
    }
    float mx = t[0];
    #pragma unroll
    for (int w = 1; w < 9; ++w) mx = fmaxf(mx, t[w]);
    float pw[9], psum = 0.0f;
    #pragma unroll
    for (int w = 0; w < 9; ++w) { pw[w] = expf(t[w] - mx); psum += pw[w]; }
    const float pinv = 1.0f / psum;

    float4 a = make_float4(0.f, 0.f, 0.f, 0.f);
    #pragma unroll
    for (int w = 0; w < 9; ++w) {
        float4 vv = *reinterpret_cast<const float4*>(&v[(bbase + start + w) * 256 + d0]);
        float s = pw[w] * pinv;
        a.x = fmaf(vv.x, s, a.x);
        a.y = fmaf(vv.y, s, a.y);
        a.z = fmaf(vv.z, s, a.z);
        a.w = fmaf(vv.w, s, a.w);
    }
    float4 xv = *reinterpret_cast<const float4*>(&x[(bbase + n) * 256 + d0]);
    float4 y = make_float4(a.x + xv.x, a.y + xv.y, a.z + xv.z, a.w + xv.w);

    float s1 = y.x + y.y + y.z + y.w;
    float s2 = y.x * y.x + y.y * y.y + y.z * y.z + y.w * y.w;
    #pragma unroll
    for (int off = 32; off > 0; off >>= 1) {
        s1 += __shfl_xor(s1, off);
        s2 += __shfl_xor(s2, off);
    }
    const float mu = s1 * (1.0f / 256.0f);
    const float var = s2 * (1.0f / 256.0f) - mu * mu;
    const float istd = 1.0f / sqrtf(var + 0.001f);

    float4 g4 = *reinterpret_cast<const float4*>(&gamma[d0]);
    float4 b4 = *reinterpret_cast<const float4*>(&beta[d0]);
    float4 o;
    o.x = (y.x - mu) * istd * g4.x + b4.x;
    o.y = (y.y - mu) * istd * g4.y + b4.y;
    o.z = (y.z - mu) * istd * g4.z + b4.z;
    o.w = (y.w - mu) * istd * g4.w + b4.w;
    *reinterpret_cast<float4*>(&out[row * 256 + d0]) = o;
}

extern "C" void kernel_launch(void* const* d_in, const int* in_sizes, int n_in,
                              void* d_out, int out_size, void* d_ws, size_t ws_size,
                              hipStream_t stream)
{
    const float* x  = (const float*)d_in[0];
    const float* Wh = (const float*)d_in[1];
    const float* bh = (const float*)d_in[2];
    const float* Wd = (const float*)d_in[3];
    const float* bd = (const float*)d_in[4];
    const float* Wv = (const float*)d_in[5];
    const float* bv = (const float*)d_in[6];
    const float* g  = (const float*)d_in[7];
    const float* be = (const float*)d_in[8];
    float* out = (float*)d_out;

    char* ws = (char*)d_ws;
    float*          z     = (float*)ws;                       // 33554432 B
    float*          v     = (float*)(ws + 33554432);          // 33554432 B
    float*          simv  = (float*)(ws + 67108864);          // 131072 B
    int*            order = (int*)(ws + 67239936);            // 131072 B
    unsigned short* WdT   = (unsigned short*)(ws + 67371008); // 1048576 B
    unsigned short* WhH   = (unsigned short*)(ws + 68419584); // 1048576 B
    float*          WhT   = (float*)(ws + 69468160);          // 2097152 B
    unsigned short* WvT   = (unsigned short*)(ws + 71565312); // 131072 B
    unsigned short* q     = (unsigned short*)(ws + 71696384); // 134217728 B
    int*            gcnt  = (int*)(ws + 205914112);           // 32768 B
    int*            gls   = (int*)(ws + 205946880);           // 10485760 B -> end 216432640

    const bool big = ws_size >= 216432640ULL;
    const int rows = Bc * Nc;                                 // 32768

    k0_wdt<<<dim3(128), dim3(256), 0, stream>>>(Wd, WdT);
    k0_wht<<<dim3(128), dim3(256), 0, stream>>>(Wh, WhH, WhT);
    k0_wvt<<<dim3(16), dim3(256), 0, stream>>>(Wv, WvT);
    if (big) {
        hipMemsetAsync(gcnt, 0, 32768, stream);
        k1a_head<<<dim3(1024, 8), dim3(256), 0, stream>>>(x, bh, WhH, q, gcnt, gls);
        k1b_down<<<dim3(1024), dim3(256), 0, stream>>>(q, WdT, bd, x, WhT, bh, gcnt, gls, z, simv);
    } else {
        k1_fused<<<dim3(rows / 32), dim3(256), 0, stream>>>(x, bh, WhT, WhH, WdT, bd, z, simv);
    }
    k2_rank<<<dim3(Bc * 16), dim3(256), 0, stream>>>(simv, order);
    k3_value<<<dim3(rows / 32), dim3(256), 0, stream>>>(z, order, WvT, bv, v);
    k4_attn_ln<<<dim3(rows / 4), dim3(256), 0, stream>>>(z, v, order, x, g, be, out);
}